// Round 1
// baseline (852.647 us; speedup 1.0000x reference)
//
#include <hip/hip_runtime.h>
#include <hip/hip_bf16.h>
#include <math.h>

#define NN   8192
#define TT   32
#define DMM  128
#define DIN  4096
#define MME  1024
#define NNZK 131072
#define EPSV 1e-5f

__device__ __forceinline__ float lrelu(float v){ return v > 0.f ? v : 0.2f*v; }

// ---------------------------------------------------------------- utilities
__global__ void zero_i(int* p, int n){ int i = blockIdx.x*256 + threadIdx.x; if (i < n) p[i] = 0; }
__global__ void zero_f(float* p, int n){ int i = blockIdx.x*256 + threadIdx.x; if (i < n) p[i] = 0.f; }
__global__ void copy_i(const int* a, int* b, int n){ int i = blockIdx.x*256 + threadIdx.x; if (i < n) b[i] = a[i]; }

__global__ void count_seg(const int* __restrict__ he_n, const int* __restrict__ he_e,
                          int* __restrict__ ncnt, int* __restrict__ ecnt){
    int k = blockIdx.x*256 + threadIdx.x;
    if (k < NNZK){ atomicAdd(&ecnt[he_e[k]], 1); atomicAdd(&ncnt[he_n[k]], 1); }
}

// single-block exclusive scan (n up to a few * 1024), 1024 threads
__global__ void scan_excl(const int* __restrict__ cnt, int* __restrict__ off, int n){
    __shared__ int buf[1024];
    __shared__ int carry;
    int t = threadIdx.x;
    if (t == 0) carry = 0;
    __syncthreads();
    for (int base = 0; base < n; base += 1024){
        int i = base + t;
        int v = (i < n) ? cnt[i] : 0;
        buf[t] = v; __syncthreads();
        for (int s = 1; s < 1024; s <<= 1){
            int tmp = (t >= s) ? buf[t - s] : 0;
            __syncthreads();
            buf[t] += tmp;
            __syncthreads();
        }
        if (i < n) off[i] = carry + buf[t] - v;
        __syncthreads();
        if (t == 1023) carry += buf[1023];
        __syncthreads();
    }
    if (t == 0) off[n] = carry;
}

__global__ void fill_perm(const int* __restrict__ seg, int* __restrict__ cur, int* __restrict__ perm){
    int k = blockIdx.x*256 + threadIdx.x;
    if (k < NNZK){ int p = atomicAdd(&cur[seg[k]], 1); perm[p] = k; }
}

// ---------------------------------------------------------------- GEMM
// C[M,N] = A[M,K] @ B[K,N]; EPI 0: raw, 1: lrelu(AB+bias), 2: add + lrelu(AB+bias)
template<int EPI>
__global__ __launch_bounds__(256) void gemm64(const float* __restrict__ A, const float* __restrict__ B,
                       const float* __restrict__ bias, const float* __restrict__ add,
                       float* __restrict__ C, int Mr, int Nc, int K){
    __shared__ float As[16][64];
    __shared__ float Bs[16][64];
    int tid = threadIdx.x;
    int m0 = blockIdx.y*64, n0 = blockIdx.x*64;
    int tx = tid & 15, ty = tid >> 4;
    int ar = tid >> 2,  ac = (tid & 3) * 4;
    int br = tid >> 4,  bc = (tid & 15) * 4;
    const float* Aptr = A + (size_t)(m0 + ar)*K + ac;
    const float* Bptr = B + (size_t)br*Nc + n0 + bc;
    float acc[4][4] = {};
    for (int k0 = 0; k0 < K; k0 += 16){
        float4 a4 = *(const float4*)(Aptr + k0);
        float4 b4 = *(const float4*)(Bptr + (size_t)k0*Nc);
        As[ac+0][ar] = a4.x; As[ac+1][ar] = a4.y; As[ac+2][ar] = a4.z; As[ac+3][ar] = a4.w;
        *(float4*)&Bs[br][bc] = b4;
        __syncthreads();
#pragma unroll
        for (int kk = 0; kk < 16; kk++){
            float4 av = *(const float4*)&As[kk][ty*4];
            float4 bv = *(const float4*)&Bs[kk][tx*4];
            float aa[4] = {av.x, av.y, av.z, av.w};
            float bb[4] = {bv.x, bv.y, bv.z, bv.w};
#pragma unroll
            for (int i = 0; i < 4; i++)
#pragma unroll
                for (int j = 0; j < 4; j++)
                    acc[i][j] += aa[i]*bb[j];
        }
        __syncthreads();
    }
    int c0 = n0 + tx*4;
#pragma unroll
    for (int i = 0; i < 4; i++){
        int r = m0 + ty*4 + i;
        float4 v;
        float* vv = (float*)&v;
#pragma unroll
        for (int j = 0; j < 4; j++){
            float tval = acc[i][j];
            if (EPI >= 1){ tval += bias[c0+j]; tval = lrelu(tval); }
            if (EPI == 2){ tval += add[(size_t)r*Nc + c0 + j]; }
            vv[j] = tval;
        }
        *(float4*)&C[(size_t)r*Nc + c0] = v;
    }
}

// ---------------------------------------------------------------- BatchNorm
__global__ void bn_stats(const float* __restrict__ x, float* __restrict__ stats, int rows){
    int c = threadIdx.x & 127, g = threadIdx.x >> 7;  // 256 threads
    float s = 0.f, q = 0.f;
    for (int r = blockIdx.x*2 + g; r < rows; r += gridDim.x*2){
        float v = x[(size_t)r*128 + c]; s += v; q += v*v;
    }
    __shared__ float S[256], Q[256];
    S[threadIdx.x] = s; Q[threadIdx.x] = q; __syncthreads();
    if (threadIdx.x < 128){
        atomicAdd(&stats[c],       S[threadIdx.x] + S[threadIdx.x+128]);
        atomicAdd(&stats[128 + c], Q[threadIdx.x] + Q[threadIdx.x+128]);
    }
}

__global__ void bn_finalize(float* stats, const float* __restrict__ g, const float* __restrict__ b, float invR){
    int c = threadIdx.x;  // 128
    float m = stats[c]*invR;
    float v = stats[128+c]*invR - m*m;
    float sc = g[c]*rsqrtf(v + EPSV);
    stats[256+c] = sc;
    stats[384+c] = b[c] - m*sc;
}

__global__ void bn_apply4(float4* __restrict__ x, const float* __restrict__ stats, size_t n4){
    size_t i = (size_t)blockIdx.x*blockDim.x + threadIdx.x;
    size_t stride = (size_t)gridDim.x*blockDim.x;
    for (; i < n4; i += stride){
        int c0 = (int)(i & 31) * 4;
        float4 v = x[i];
        v.x = v.x*stats[256+c0+0] + stats[384+c0+0];
        v.y = v.y*stats[256+c0+1] + stats[384+c0+1];
        v.z = v.z*stats[256+c0+2] + stats[384+c0+2];
        v.w = v.w*stats[256+c0+3] + stats[384+c0+3];
        x[i] = v;
    }
}

// ---------------------------------------------------------------- segment ops
// he_attr[m,c] = sum over incidences of h[node,c]
__global__ void seg_sum_edge(const int* __restrict__ eoff, const int* __restrict__ eperm,
                             const int* __restrict__ he_n, const float* __restrict__ h,
                             float* __restrict__ out){
    int m = blockIdx.x, c = threadIdx.x;  // 128
    int s0 = eoff[m], cnt = eoff[m+1] - s0;
    __shared__ int sn[128];
    float acc = 0.f;
    for (int base = 0; base < cnt; base += 128){
        int i = base + c;
        if (i < cnt) sn[c] = he_n[eperm[s0+i]];
        __syncthreads();
        int lim = min(128, cnt - base);
        for (int j = 0; j < lim; j++) acc += h[(size_t)sn[j]*128 + c];
        __syncthreads();
    }
    out[(size_t)m*128 + c] = acc;
}

// out[row,h] = sum_f xt[row, h*128+f] * att[h*256 + aoff + f]
template<int H>
__global__ void row_att(const float* __restrict__ xt, const float* __restrict__ att,
                        int aoff, float* __restrict__ out){
    int n = blockIdx.x, lane = threadIdx.x;  // 64
#pragma unroll
    for (int h = 0; h < H; h++){
        const float* xr = xt + (size_t)n*(H*128) + h*128;
        const float* ar = att + h*256 + aoff;
        float s = xr[lane]*ar[lane] + xr[lane+64]*ar[lane+64];
        for (int d = 32; d > 0; d >>= 1) s += __shfl_down(s, d);
        if (lane == 0) out[n*H + h] = s;
    }
}

template<int H>
__global__ void seg_softmax(const int* __restrict__ eoff, const int* __restrict__ eperm,
                            const int* __restrict__ he_n,
                            const float* __restrict__ ax, const float* __restrict__ ae,
                            float* __restrict__ alpha){
    int m = blockIdx.x, t = threadIdx.x;  // 128
    int s0 = eoff[m], cnt = eoff[m+1] - s0;
    if (cnt == 0) return;
    __shared__ float red[128];
    float aeh[H];
#pragma unroll
    for (int h = 0; h < H; h++) aeh[h] = ae[m*H + h];
    float lmax[H];
#pragma unroll
    for (int h = 0; h < H; h++) lmax[h] = -1e30f;
    for (int i = t; i < cnt; i += 128){
        int k = eperm[s0+i]; int n = he_n[k];
#pragma unroll
        for (int h = 0; h < H; h++){
            float v = lrelu(ax[n*H + h] + aeh[h]);
            alpha[(size_t)k*H + h] = v;
            lmax[h] = fmaxf(lmax[h], v);
        }
    }
    float gmax[H];
#pragma unroll
    for (int h = 0; h < H; h++){
        red[t] = lmax[h]; __syncthreads();
        for (int s = 64; s > 0; s >>= 1){ if (t < s) red[t] = fmaxf(red[t], red[t+s]); __syncthreads(); }
        gmax[h] = red[0]; __syncthreads();
    }
    float lsum[H];
#pragma unroll
    for (int h = 0; h < H; h++) lsum[h] = 0.f;
    for (int i = t; i < cnt; i += 128){
        int k = eperm[s0+i];
#pragma unroll
        for (int h = 0; h < H; h++){
            float ex = __expf(alpha[(size_t)k*H + h] - gmax[h]);
            alpha[(size_t)k*H + h] = ex;
            lsum[h] += ex;
        }
    }
    float ginv[H];
#pragma unroll
    for (int h = 0; h < H; h++){
        red[t] = lsum[h]; __syncthreads();
        for (int s = 64; s > 0; s >>= 1){ if (t < s) red[t] += red[t+s]; __syncthreads(); }
        ginv[h] = 1.f/red[0]; __syncthreads();
    }
    for (int i = t; i < cnt; i += 128){
        int k = eperm[s0+i];
#pragma unroll
        for (int h = 0; h < H; h++) alpha[(size_t)k*H + h] *= ginv[h];
    }
}

// eo[m,h,c] = (1/cnt) * sum_i alpha[k,h]*xt[n_k, h*128+c]
template<int H>
__global__ void seg_eo(const int* __restrict__ eoff, const int* __restrict__ eperm,
                       const int* __restrict__ he_n,
                       const float* __restrict__ alpha, const float* __restrict__ xt,
                       float* __restrict__ eo){
    int m = blockIdx.x, c = threadIdx.x;  // 128
    int s0 = eoff[m], cnt = eoff[m+1] - s0;
    __shared__ int sn[128];
    __shared__ float sa[128][H];
    float acc[H] = {};
    for (int base = 0; base < cnt; base += 128){
        int i = base + c;
        if (i < cnt){
            int k = eperm[s0+i];
            sn[c] = he_n[k];
#pragma unroll
            for (int h = 0; h < H; h++) sa[c][h] = alpha[(size_t)k*H + h];
        }
        __syncthreads();
        int lim = min(128, cnt - base);
        for (int j = 0; j < lim; j++){
            const float* xr = xt + (size_t)sn[j]*(128*H);
#pragma unroll
            for (int h = 0; h < H; h++) acc[h] += sa[j][h]*xr[h*128 + c];
        }
        __syncthreads();
    }
    float binv = cnt > 0 ? 1.f/(float)cnt : 0.f;
#pragma unroll
    for (int h = 0; h < H; h++) eo[(size_t)m*(128*H) + h*128 + c] = acc[h]*binv;
}

// hout[n,c] = hin[n,c] + bias[c] + (1/(cnt*H)) * sum_i sum_h alpha[k,h]*eo[e_k,h,c]
template<int H>
__global__ void seg_node_out(const int* __restrict__ noff, const int* __restrict__ nperm,
                             const int* __restrict__ he_e,
                             const float* __restrict__ alpha, const float* __restrict__ eo,
                             const float* __restrict__ hin, const float* __restrict__ bias,
                             float* __restrict__ hout){
    int n = blockIdx.x, c = threadIdx.x;  // 128
    int s0 = noff[n], cnt = noff[n+1] - s0;
    float acc = 0.f;
    for (int i = 0; i < cnt; i++){
        int k = nperm[s0+i]; int e = he_e[k];
        const float* er = eo + (size_t)e*(128*H);
#pragma unroll
        for (int h = 0; h < H; h++) acc += alpha[(size_t)k*H + h]*er[h*128 + c];
    }
    float dinv = cnt > 0 ? 1.f/((float)cnt*(float)H) : 0.f;
    hout[(size_t)n*128 + c] = hin[(size_t)n*128 + c] + bias[c] + acc*dinv;
}

// ---------------------------------------------------------------- launcher
extern "C" void kernel_launch(void* const* d_in, const int* in_sizes, int n_in,
                              void* d_out, int out_size, void* d_ws, size_t ws_size,
                              hipStream_t stream){
    const float* x    = (const float*)d_in[0];
    const int*   he_n = (const int*)  d_in[1];
    const int*   he_e = (const int*)  d_in[2];
    const float* W1   = (const float*)d_in[3];
    const float* b1   = (const float*)d_in[4];
    const float* g1   = (const float*)d_in[5];
    const float* be1  = (const float*)d_in[6];
    const float* Wh1  = (const float*)d_in[7];
    const float* att1 = (const float*)d_in[8];
    const float* bh1  = (const float*)d_in[9];
    const float* g2   = (const float*)d_in[10];
    const float* be2  = (const float*)d_in[11];
    const float* Wh2  = (const float*)d_in[12];
    const float* att2 = (const float*)d_in[13];
    const float* bh2  = (const float*)d_in[14];
    const float* g3   = (const float*)d_in[15];
    const float* be3  = (const float*)d_in[16];
    const float* W3   = (const float*)d_in[17];
    const float* b3   = (const float*)d_in[18];
    const float* g4   = (const float*)d_in[19];
    const float* be4  = (const float*)d_in[20];
    float* out = (float*)d_out;

    char* ws = (char*)d_ws;
    size_t off = 0;
    auto alloc = [&](size_t bytes)->char*{ char* p = ws + off; off += (bytes + 255) & ~(size_t)255; return p; };

    float* h1      = (float*)alloc((size_t)NN*128*4);
    float* h2      = (float*)alloc((size_t)NN*128*4);
    float* h3      = (float*)alloc((size_t)NN*128*4);
    float* xt      = (float*)alloc((size_t)NN*512*4);
    float* et      = (float*)alloc((size_t)MME*512*4);
    float* heattr  = (float*)alloc((size_t)MME*128*4);
    float* alpha   = (float*)alloc((size_t)NNZK*4*4);
    float* eo      = (float*)alloc((size_t)MME*512*4);
    float* ax      = (float*)alloc((size_t)NN*4*4);
    float* ae      = (float*)alloc((size_t)MME*4*4);
    float* stats   = (float*)alloc(512*4);
    int*   ecnt    = (int*)alloc(MME*4);
    int*   eoffb   = (int*)alloc((MME+1)*4);
    int*   ecur    = (int*)alloc(MME*4);
    int*   ncnt    = (int*)alloc(NN*4);
    int*   noffb   = (int*)alloc((NN+1)*4);
    int*   ncur    = (int*)alloc(NN*4);
    int*   eperm   = (int*)alloc((size_t)NNZK*4);
    int*   nperm   = (int*)alloc((size_t)NNZK*4);

    // ---- CSR build ----
    zero_i<<<(MME+NN+255)/256, 256, 0, stream>>>(ecnt, MME);   // ecnt
    zero_i<<<(NN+255)/256, 256, 0, stream>>>(ncnt, NN);        // ncnt
    count_seg<<<NNZK/256, 256, 0, stream>>>(he_n, he_e, ncnt, ecnt);
    scan_excl<<<1, 1024, 0, stream>>>(ecnt, eoffb, MME);
    scan_excl<<<1, 1024, 0, stream>>>(ncnt, noffb, NN);
    copy_i<<<(MME+255)/256, 256, 0, stream>>>(eoffb, ecur, MME);
    copy_i<<<(NN+255)/256, 256, 0, stream>>>(noffb, ncur, NN);
    fill_perm<<<NNZK/256, 256, 0, stream>>>(he_e, ecur, eperm);
    fill_perm<<<NNZK/256, 256, 0, stream>>>(he_n, ncur, nperm);

    // ---- layer 0: h1 = lrelu(x @ W1 + b1); BN1 ----
    gemm64<1><<<dim3(128/64, NN/64), 256, 0, stream>>>(x, W1, b1, nullptr, h1, NN, 128, DIN);
    zero_f<<<1, 256, 0, stream>>>(stats, 256);
    bn_stats<<<128, 256, 0, stream>>>(h1, stats, NN);
    bn_finalize<<<1, 128, 0, stream>>>(stats, g1, be1, 1.f/NN);
    bn_apply4<<<1024, 256, 0, stream>>>((float4*)h1, stats, (size_t)NN*32);

    // ---- hconv1 (heads=4) ----
    seg_sum_edge<<<MME, 128, 0, stream>>>(eoffb, eperm, he_n, h1, heattr);
    gemm64<0><<<dim3(512/64, NN/64), 256, 0, stream>>>(h1, Wh1, nullptr, nullptr, xt, NN, 512, 128);
    gemm64<0><<<dim3(512/64, MME/64), 256, 0, stream>>>(heattr, Wh1, nullptr, nullptr, et, MME, 512, 128);
    row_att<4><<<NN, 64, 0, stream>>>(xt, att1, 0, ax);
    row_att<4><<<MME, 64, 0, stream>>>(et, att1, 128, ae);
    seg_softmax<4><<<MME, 128, 0, stream>>>(eoffb, eperm, he_n, ax, ae, alpha);
    seg_eo<4><<<MME, 128, 0, stream>>>(eoffb, eperm, he_n, alpha, xt, eo);
    seg_node_out<4><<<NN, 128, 0, stream>>>(noffb, nperm, he_e, alpha, eo, h1, bh1, h2);
    zero_f<<<1, 256, 0, stream>>>(stats, 256);
    bn_stats<<<128, 256, 0, stream>>>(h2, stats, NN);
    bn_finalize<<<1, 128, 0, stream>>>(stats, g2, be2, 1.f/NN);
    bn_apply4<<<1024, 256, 0, stream>>>((float4*)h2, stats, (size_t)NN*32);

    // ---- hconv2 (heads=1) ----
    seg_sum_edge<<<MME, 128, 0, stream>>>(eoffb, eperm, he_n, h2, heattr);
    gemm64<0><<<dim3(128/64, NN/64), 256, 0, stream>>>(h2, Wh2, nullptr, nullptr, xt, NN, 128, 128);
    gemm64<0><<<dim3(128/64, MME/64), 256, 0, stream>>>(heattr, Wh2, nullptr, nullptr, et, MME, 128, 128);
    row_att<1><<<NN, 64, 0, stream>>>(xt, att2, 0, ax);
    row_att<1><<<MME, 64, 0, stream>>>(et, att2, 128, ae);
    seg_softmax<1><<<MME, 128, 0, stream>>>(eoffb, eperm, he_n, ax, ae, alpha);
    seg_eo<1><<<MME, 128, 0, stream>>>(eoffb, eperm, he_n, alpha, xt, eo);
    seg_node_out<1><<<NN, 128, 0, stream>>>(noffb, nperm, he_e, alpha, eo, h2, bh2, h3);
    zero_f<<<1, 256, 0, stream>>>(stats, 256);
    bn_stats<<<128, 256, 0, stream>>>(h3, stats, NN);
    bn_finalize<<<1, 128, 0, stream>>>(stats, g3, be3, 1.f/NN);
    bn_apply4<<<1024, 256, 0, stream>>>((float4*)h3, stats, (size_t)NN*32);

    // ---- final: out = BN4(x + lrelu(h3 @ W3 + b3)) ----
    gemm64<2><<<dim3(DIN/64, NN/64), 256, 0, stream>>>(h3, W3, b3, x, out, NN, DIN, 128);
    zero_f<<<1, 256, 0, stream>>>(stats, 256);
    bn_stats<<<1024, 256, 0, stream>>>(out, stats, NN*TT);
    bn_finalize<<<1, 128, 0, stream>>>(stats, g4, be4, 1.f/((float)NN*TT));
    bn_apply4<<<2048, 256, 0, stream>>>((float4*)out, stats, (size_t)NN*TT*32);
}

// Round 2
// 580.411 us; speedup vs baseline: 1.4690x; 1.4690x over previous
//
#include <hip/hip_runtime.h>
#include <hip/hip_bf16.h>
#include <math.h>

#define NN   8192
#define TT   32
#define DIN  4096
#define MME  1024
#define NNZK 131072
#define EPSV 1e-5f
#define MALL (NN + MME)   // 9216 combined node+edge rows

typedef __attribute__((ext_vector_type(8))) short bf16x8;
typedef __attribute__((ext_vector_type(4))) float f32x4;

__device__ __forceinline__ float lrelu(float v){ return v > 0.f ? v : 0.2f*v; }
__device__ __forceinline__ short f2b(float f){
    union { __hip_bfloat16 h; short s; } u; u.h = __float2bfloat16(f); return u.s;
}

// ---------------------------------------------------------------- utilities
__global__ void zero_i(int* p, int n){ int i = blockIdx.x*256 + threadIdx.x; if (i < n) p[i] = 0; }
__global__ void zero_f(float* p, int n){ int i = blockIdx.x*256 + threadIdx.x; if (i < n) p[i] = 0.f; }
__global__ void copy_i(const int* a, int* b, int n){ int i = blockIdx.x*256 + threadIdx.x; if (i < n) b[i] = a[i]; }

__global__ void count_seg(const int* __restrict__ he_n, const int* __restrict__ he_e,
                          int* __restrict__ ncnt, int* __restrict__ ecnt){
    int k = blockIdx.x*256 + threadIdx.x;
    if (k < NNZK){ atomicAdd(&ecnt[he_e[k]], 1); atomicAdd(&ncnt[he_n[k]], 1); }
}

__global__ void scan_excl(const int* __restrict__ cnt, int* __restrict__ off, int n){
    __shared__ int buf[1024];
    __shared__ int carry;
    int t = threadIdx.x;
    if (t == 0) carry = 0;
    __syncthreads();
    for (int base = 0; base < n; base += 1024){
        int i = base + t;
        int v = (i < n) ? cnt[i] : 0;
        buf[t] = v; __syncthreads();
        for (int s = 1; s < 1024; s <<= 1){
            int tmp = (t >= s) ? buf[t - s] : 0;
            __syncthreads();
            buf[t] += tmp;
            __syncthreads();
        }
        if (i < n) off[i] = carry + buf[t] - v;
        __syncthreads();
        if (t == 1023) carry += buf[1023];
        __syncthreads();
    }
    if (t == 0) off[n] = carry;
}

__global__ void fill_perm(const int* __restrict__ seg, int* __restrict__ cur, int* __restrict__ perm){
    int k = blockIdx.x*256 + threadIdx.x;
    if (k < NNZK){ int p = atomicAdd(&cur[seg[k]], 1); perm[p] = k; }
}

// ------------------------------------------------ weight convert + transpose
// W[K,N] fp32 -> BT[N,K] bf16
__global__ void wconv_t(const float* __restrict__ W, __hip_bfloat16* __restrict__ BT, int K, int N){
    __shared__ float tile[32][33];
    int k0 = blockIdx.y*32, n0 = blockIdx.x*32;
    int tx = threadIdx.x & 31, ty = threadIdx.x >> 5;
    for (int i = ty; i < 32; i += 8) tile[i][tx] = W[(size_t)(k0+i)*N + n0+tx];
    __syncthreads();
    for (int i = ty; i < 32; i += 8)
        BT[(size_t)(n0+i)*K + k0 + tx] = __float2bfloat16(tile[tx][i]);
}

// ---------------------------------------------------------------- MFMA GEMM
// C[M,N] = A_fp32[M,K] @ B, with B given as BT_bf16[N,K] (K-major).
// A converted fp32->bf16 in-register during staging.
// 128x128 tile, BK=32, 4 waves, 16x16x32 MFMA, swizzled LDS.
// EPI 0: plain store (split-K partial slice via blockIdx.z)
// EPI 2: C = lrelu(AB + bias[col]) + add[row,col]
#define SWZ(b) ((b) ^ ((((b) >> 6) & 7) << 4))

template<int EPI>
__global__ __launch_bounds__(256) void gemm_mfma(
    const float* __restrict__ A, const __hip_bfloat16* __restrict__ BT,
    float* __restrict__ C, const float* __restrict__ bias, const float* __restrict__ add,
    int M, int N, int K, int kchunk)
{
    __shared__ f32x4 AsRaw[512];   // 8 KB, 16B-aligned
    __shared__ f32x4 BsRaw[512];   // 8 KB
    char* As = (char*)AsRaw;
    char* Bs = (char*)BsRaw;
    const int tid = threadIdx.x;
    const int lane = tid & 63;
    const int w = tid >> 6;
    const int m0 = blockIdx.y << 7, n0 = blockIdx.x << 7;
    const int kz = blockIdx.z * kchunk;
    const int wr = (w >> 1) << 6, wc = (w & 1) << 6;

    // staging slots: slot s covers tile row r=s>>2, k-bytes [(s&3)*16, +16)
    const int s0 = tid, s1 = tid + 256;
    const int r0 = s0 >> 2, k0b = (s0 & 3) << 3;   // k offset in elements
    const int r1 = s1 >> 2, k1b = (s1 & 3) << 3;
    const float* pA0 = A + (size_t)(m0 + r0)*K + kz + k0b;
    const float* pA1 = A + (size_t)(m0 + r1)*K + kz + k1b;
    const __hip_bfloat16* pB0 = BT + (size_t)(n0 + r0)*K + kz + k0b;
    const __hip_bfloat16* pB1 = BT + (size_t)(n0 + r1)*K + kz + k1b;
    const int wo0 = SWZ(s0 << 4), wo1 = SWZ(s1 << 4);

    // fragment read byte-offsets (swizzled), compile-time-indexed
    int raOff[4], rbOff[4];
#pragma unroll
    for (int f = 0; f < 4; f++){
        int rowA = wr + f*16 + (lane & 15);
        raOff[f] = SWZ(rowA*64 + ((lane >> 4) << 4));
        int rowB = wc + f*16 + (lane & 15);
        rbOff[f] = SWZ(rowB*64 + ((lane >> 4) << 4));
    }

    f32x4 acc[4][4] = {};

    // prologue prefetch
    float4 a0l = *(const float4*)pA0, a0h = *(const float4*)(pA0+4);
    float4 a1l = *(const float4*)pA1, a1h = *(const float4*)(pA1+4);
    bf16x8 b0 = *(const bf16x8*)pB0, b1 = *(const bf16x8*)pB1;

    const int nsteps = kchunk >> 5;
    for (int ks = 0; ks < nsteps; ks++){
        bf16x8 va0, va1;
        va0[0]=f2b(a0l.x); va0[1]=f2b(a0l.y); va0[2]=f2b(a0l.z); va0[3]=f2b(a0l.w);
        va0[4]=f2b(a0h.x); va0[5]=f2b(a0h.y); va0[6]=f2b(a0h.z); va0[7]=f2b(a0h.w);
        va1[0]=f2b(a1l.x); va1[1]=f2b(a1l.y); va1[2]=f2b(a1l.z); va1[3]=f2b(a1l.w);
        va1[4]=f2b(a1h.x); va1[5]=f2b(a1h.y); va1[6]=f2b(a1h.z); va1[7]=f2b(a1h.w);
        __syncthreads();                       // prev iter's LDS reads done
        *(bf16x8*)(As + wo0) = va0;
        *(bf16x8*)(As + wo1) = va1;
        *(bf16x8*)(Bs + wo0) = b0;
        *(bf16x8*)(Bs + wo1) = b1;
        __syncthreads();
        if (ks + 1 < nsteps){                  // prefetch next chunk (hidden under MFMA)
            pA0 += 32; pA1 += 32; pB0 += 32; pB1 += 32;
            a0l = *(const float4*)pA0; a0h = *(const float4*)(pA0+4);
            a1l = *(const float4*)pA1; a1h = *(const float4*)(pA1+4);
            b0 = *(const bf16x8*)pB0;  b1 = *(const bf16x8*)pB1;
        }
        bf16x8 af[4], bfr[4];
#pragma unroll
        for (int f = 0; f < 4; f++){
            af[f]  = *(const bf16x8*)(As + raOff[f]);
            bfr[f] = *(const bf16x8*)(Bs + rbOff[f]);
        }
#pragma unroll
        for (int mf = 0; mf < 4; mf++)
#pragma unroll
            for (int nf = 0; nf < 4; nf++)
                acc[mf][nf] = __builtin_amdgcn_mfma_f32_16x16x32_bf16(af[mf], bfr[nf], acc[mf][nf], 0, 0, 0);
    }

    float* Cz = C + (size_t)blockIdx.z * ((size_t)M * (size_t)N);
#pragma unroll
    for (int mf = 0; mf < 4; mf++){
#pragma unroll
        for (int nf = 0; nf < 4; nf++){
            int col = n0 + wc + nf*16 + (lane & 15);
#pragma unroll
            for (int r = 0; r < 4; r++){
                int row = m0 + wr + mf*16 + ((lane >> 4) << 2) + r;
                float v = acc[mf][nf][r];
                if (EPI == 2){
                    v += bias[col]; v = lrelu(v);
                    v += add[(size_t)row*N + col];
                }
                Cz[(size_t)row*N + col] = v;
            }
        }
    }
}

// split-K reduce + bias + lrelu (row length 128 floats)
__global__ void reduce8(const float* __restrict__ part, const float* __restrict__ bias,
                        float* __restrict__ out, int nf4, int parts){
    int i = blockIdx.x*256 + threadIdx.x;
    if (i >= nf4) return;
    float4 s = ((const float4*)part)[i];
    for (int z = 1; z < parts; z++){
        float4 p = ((const float4*)part)[(size_t)z*nf4 + i];
        s.x += p.x; s.y += p.y; s.z += p.z; s.w += p.w;
    }
    int c0 = (i & 31) << 2;
    s.x = lrelu(s.x + bias[c0+0]); s.y = lrelu(s.y + bias[c0+1]);
    s.z = lrelu(s.z + bias[c0+2]); s.w = lrelu(s.w + bias[c0+3]);
    ((float4*)out)[i] = s;
}

// ---------------------------------------------------------------- BatchNorm
__global__ void bn_stats(const float* __restrict__ x, float* __restrict__ stats, int rows){
    int c = threadIdx.x & 127, g = threadIdx.x >> 7;
    float s = 0.f, q = 0.f;
    for (int r = blockIdx.x*2 + g; r < rows; r += gridDim.x*2){
        float v = x[(size_t)r*128 + c]; s += v; q += v*v;
    }
    __shared__ float S[256], Q[256];
    S[threadIdx.x] = s; Q[threadIdx.x] = q; __syncthreads();
    if (threadIdx.x < 128){
        atomicAdd(&stats[c],       S[threadIdx.x] + S[threadIdx.x+128]);
        atomicAdd(&stats[128 + c], Q[threadIdx.x] + Q[threadIdx.x+128]);
    }
}

__global__ void bn_finalize(float* stats, const float* __restrict__ g, const float* __restrict__ b, float invR){
    int c = threadIdx.x;
    float m = stats[c]*invR;
    float v = stats[128+c]*invR - m*m;
    float sc = g[c]*rsqrtf(v + EPSV);
    stats[256+c] = sc;
    stats[384+c] = b[c] - m*sc;
}

__global__ void bn_apply4(float4* __restrict__ x, const float* __restrict__ stats, size_t n4){
    size_t i = (size_t)blockIdx.x*blockDim.x + threadIdx.x;
    size_t stride = (size_t)gridDim.x*blockDim.x;
    for (; i < n4; i += stride){
        int c0 = (int)(i & 31) * 4;
        float4 v = x[i];
        v.x = v.x*stats[256+c0+0] + stats[384+c0+0];
        v.y = v.y*stats[256+c0+1] + stats[384+c0+1];
        v.z = v.z*stats[256+c0+2] + stats[384+c0+2];
        v.w = v.w*stats[256+c0+3] + stats[384+c0+3];
        x[i] = v;
    }
}

// ---------------------------------------------------------------- segment ops
__global__ void seg_sum_edge(const int* __restrict__ eoff, const int* __restrict__ eperm,
                             const int* __restrict__ he_n, const float* __restrict__ h,
                             float* __restrict__ out){
    int m = blockIdx.x, c = threadIdx.x;
    int s0 = eoff[m], cnt = eoff[m+1] - s0;
    __shared__ int sn[128];
    float acc = 0.f;
    for (int base = 0; base < cnt; base += 128){
        int i = base + c;
        if (i < cnt) sn[c] = he_n[eperm[s0+i]];
        __syncthreads();
        int lim = min(128, cnt - base);
        for (int j = 0; j < lim; j++) acc += h[(size_t)sn[j]*128 + c];
        __syncthreads();
    }
    out[(size_t)m*128 + c] = acc;
}

template<int H>
__global__ void row_att(const float* __restrict__ xt, const float* __restrict__ att,
                        int aoff, float* __restrict__ out){
    int n = blockIdx.x, lane = threadIdx.x;
#pragma unroll
    for (int h = 0; h < H; h++){
        const float* xr = xt + (size_t)n*(H*128) + h*128;
        const float* ar = att + h*256 + aoff;
        float s = xr[lane]*ar[lane] + xr[lane+64]*ar[lane+64];
        for (int d = 32; d > 0; d >>= 1) s += __shfl_down(s, d);
        if (lane == 0) out[n*H + h] = s;
    }
}

template<int H>
__global__ void seg_softmax(const int* __restrict__ eoff, const int* __restrict__ eperm,
                            const int* __restrict__ he_n,
                            const float* __restrict__ ax, const float* __restrict__ ae,
                            float* __restrict__ alpha){
    int m = blockIdx.x, t = threadIdx.x;
    int s0 = eoff[m], cnt = eoff[m+1] - s0;
    if (cnt == 0) return;
    __shared__ float red[128];
    float aeh[H];
#pragma unroll
    for (int h = 0; h < H; h++) aeh[h] = ae[m*H + h];
    float lmax[H];
#pragma unroll
    for (int h = 0; h < H; h++) lmax[h] = -1e30f;
    for (int i = t; i < cnt; i += 128){
        int k = eperm[s0+i]; int n = he_n[k];
#pragma unroll
        for (int h = 0; h < H; h++){
            float v = lrelu(ax[n*H + h] + aeh[h]);
            alpha[(size_t)k*H + h] = v;
            lmax[h] = fmaxf(lmax[h], v);
        }
    }
    float gmax[H];
#pragma unroll
    for (int h = 0; h < H; h++){
        red[t] = lmax[h]; __syncthreads();
        for (int s = 64; s > 0; s >>= 1){ if (t < s) red[t] = fmaxf(red[t], red[t+s]); __syncthreads(); }
        gmax[h] = red[0]; __syncthreads();
    }
    float lsum[H];
#pragma unroll
    for (int h = 0; h < H; h++) lsum[h] = 0.f;
    for (int i = t; i < cnt; i += 128){
        int k = eperm[s0+i];
#pragma unroll
        for (int h = 0; h < H; h++){
            float ex = __expf(alpha[(size_t)k*H + h] - gmax[h]);
            alpha[(size_t)k*H + h] = ex;
            lsum[h] += ex;
        }
    }
    float ginv[H];
#pragma unroll
    for (int h = 0; h < H; h++){
        red[t] = lsum[h]; __syncthreads();
        for (int s = 64; s > 0; s >>= 1){ if (t < s) red[t] += red[t+s]; __syncthreads(); }
        ginv[h] = 1.f/red[0]; __syncthreads();
    }
    for (int i = t; i < cnt; i += 128){
        int k = eperm[s0+i];
#pragma unroll
        for (int h = 0; h < H; h++) alpha[(size_t)k*H + h] *= ginv[h];
    }
}

template<int H>
__global__ void seg_eo(const int* __restrict__ eoff, const int* __restrict__ eperm,
                       const int* __restrict__ he_n,
                       const float* __restrict__ alpha, const float* __restrict__ xt,
                       float* __restrict__ eo){
    int m = blockIdx.x, c = threadIdx.x;
    int s0 = eoff[m], cnt = eoff[m+1] - s0;
    __shared__ int sn[128];
    __shared__ float sa[128][H];
    float acc[H] = {};
    for (int base = 0; base < cnt; base += 128){
        int i = base + c;
        if (i < cnt){
            int k = eperm[s0+i];
            sn[c] = he_n[k];
#pragma unroll
            for (int h = 0; h < H; h++) sa[c][h] = alpha[(size_t)k*H + h];
        }
        __syncthreads();
        int lim = min(128, cnt - base);
        for (int j = 0; j < lim; j++){
            const float* xr = xt + (size_t)sn[j]*(128*H);
#pragma unroll
            for (int h = 0; h < H; h++) acc[h] += sa[j][h]*xr[h*128 + c];
        }
        __syncthreads();
    }
    float binv = cnt > 0 ? 1.f/(float)cnt : 0.f;
#pragma unroll
    for (int h = 0; h < H; h++) eo[(size_t)m*(128*H) + h*128 + c] = acc[h]*binv;
}

template<int H>
__global__ void seg_node_out(const int* __restrict__ noff, const int* __restrict__ nperm,
                             const int* __restrict__ he_e,
                             const float* __restrict__ alpha, const float* __restrict__ eo,
                             const float* __restrict__ hin, const float* __restrict__ bias,
                             float* __restrict__ hout){
    int n = blockIdx.x, c = threadIdx.x;
    int s0 = noff[n], cnt = noff[n+1] - s0;
    float acc = 0.f;
    for (int i = 0; i < cnt; i++){
        int k = nperm[s0+i]; int e = he_e[k];
        const float* er = eo + (size_t)e*(128*H);
#pragma unroll
        for (int h = 0; h < H; h++) acc += alpha[(size_t)k*H + h]*er[h*128 + c];
    }
    float dinv = cnt > 0 ? 1.f/((float)cnt*(float)H) : 0.f;
    hout[(size_t)n*128 + c] = hin[(size_t)n*128 + c] + bias[c] + acc*dinv;
}

// ---------------------------------------------------------------- launcher
extern "C" void kernel_launch(void* const* d_in, const int* in_sizes, int n_in,
                              void* d_out, int out_size, void* d_ws, size_t ws_size,
                              hipStream_t stream){
    const float* x    = (const float*)d_in[0];
    const int*   he_n = (const int*)  d_in[1];
    const int*   he_e = (const int*)  d_in[2];
    const float* W1   = (const float*)d_in[3];
    const float* b1   = (const float*)d_in[4];
    const float* g1   = (const float*)d_in[5];
    const float* be1  = (const float*)d_in[6];
    const float* Wh1  = (const float*)d_in[7];
    const float* att1 = (const float*)d_in[8];
    const float* bh1  = (const float*)d_in[9];
    const float* g2   = (const float*)d_in[10];
    const float* be2  = (const float*)d_in[11];
    const float* Wh2  = (const float*)d_in[12];
    const float* att2 = (const float*)d_in[13];
    const float* bh2  = (const float*)d_in[14];
    const float* g3   = (const float*)d_in[15];
    const float* be3  = (const float*)d_in[16];
    const float* W3   = (const float*)d_in[17];
    const float* b3   = (const float*)d_in[18];
    const float* g4   = (const float*)d_in[19];
    const float* be4  = (const float*)d_in[20];
    float* out = (float*)d_out;

    char* ws = (char*)d_ws;
    size_t off = 0;
    auto alloc = [&](size_t bytes)->char*{ char* p = ws + off; off += (bytes + 255) & ~(size_t)255; return p; };

    float* hall1  = (float*)alloc((size_t)MALL*128*4);   // [h1 ; heattr1]
    float* hall2  = (float*)alloc((size_t)MALL*128*4);   // [h2 ; heattr2]
    float* h3     = (float*)alloc((size_t)NN*128*4);
    float* xt1    = (float*)alloc((size_t)MALL*512*4);   // [xt ; et] heads=4
    float* xt2    = (float*)alloc((size_t)MALL*128*4);   // [xt ; et] heads=1
    float* eo     = (float*)alloc((size_t)MME*512*4);
    float* alpha  = (float*)alloc((size_t)NNZK*4*4);
    float* ax     = (float*)alloc((size_t)NN*4*4);
    float* ae     = (float*)alloc((size_t)MME*4*4);
    float* stats  = (float*)alloc(512*4);
    float* part   = (float*)alloc((size_t)8*NN*128*4);   // split-K partials (32 MB)
    __hip_bfloat16* W1T  = (__hip_bfloat16*)alloc((size_t)128*DIN*2);
    __hip_bfloat16* Wh1T = (__hip_bfloat16*)alloc((size_t)512*128*2);
    __hip_bfloat16* Wh2T = (__hip_bfloat16*)alloc((size_t)128*128*2);
    __hip_bfloat16* W3T  = (__hip_bfloat16*)alloc((size_t)DIN*128*2);
    int* ecnt  = (int*)alloc(MME*4);
    int* eoffb = (int*)alloc((MME+1)*4);
    int* ecur  = (int*)alloc(MME*4);
    int* ncnt  = (int*)alloc(NN*4);
    int* noffb = (int*)alloc((NN+1)*4);
    int* ncur  = (int*)alloc(NN*4);
    int* eperm = (int*)alloc((size_t)NNZK*4);
    int* nperm = (int*)alloc((size_t)NNZK*4);

    // ---- CSR build ----
    zero_i<<<(MME+255)/256, 256, 0, stream>>>(ecnt, MME);
    zero_i<<<(NN+255)/256, 256, 0, stream>>>(ncnt, NN);
    count_seg<<<NNZK/256, 256, 0, stream>>>(he_n, he_e, ncnt, ecnt);
    scan_excl<<<1, 1024, 0, stream>>>(ecnt, eoffb, MME);
    scan_excl<<<1, 1024, 0, stream>>>(ncnt, noffb, NN);
    copy_i<<<(MME+255)/256, 256, 0, stream>>>(eoffb, ecur, MME);
    copy_i<<<(NN+255)/256, 256, 0, stream>>>(noffb, ncur, NN);
    fill_perm<<<NNZK/256, 256, 0, stream>>>(he_e, ecur, eperm);
    fill_perm<<<NNZK/256, 256, 0, stream>>>(he_n, ncur, nperm);

    // ---- weight transpose+convert (fp32 [K,N] -> bf16 [N,K]) ----
    wconv_t<<<dim3(128/32, DIN/32), 256, 0, stream>>>(W1,  W1T,  DIN, 128);
    wconv_t<<<dim3(512/32, 128/32), 256, 0, stream>>>(Wh1, Wh1T, 128, 512);
    wconv_t<<<dim3(128/32, 128/32), 256, 0, stream>>>(Wh2, Wh2T, 128, 128);
    wconv_t<<<dim3(DIN/32, 128/32), 256, 0, stream>>>(W3,  W3T,  128, DIN);

    // ---- layer 0: h1 = lrelu(x @ W1 + b1); BN1 ----
    gemm_mfma<0><<<dim3(1, NN/128, 8), 256, 0, stream>>>(x, W1T, part, nullptr, nullptr, NN, 128, DIN, DIN/8);
    reduce8<<<(NN*128/4 + 255)/256, 256, 0, stream>>>(part, b1, hall1, NN*128/4, 8);
    zero_f<<<1, 256, 0, stream>>>(stats, 256);
    bn_stats<<<128, 256, 0, stream>>>(hall1, stats, NN);
    bn_finalize<<<1, 128, 0, stream>>>(stats, g1, be1, 1.f/NN);
    bn_apply4<<<1024, 256, 0, stream>>>((float4*)hall1, stats, (size_t)NN*32);

    // ---- hconv1 (heads=4) ----
    seg_sum_edge<<<MME, 128, 0, stream>>>(eoffb, eperm, he_n, hall1, hall1 + (size_t)NN*128);
    gemm_mfma<0><<<dim3(512/128, MALL/128, 1), 256, 0, stream>>>(hall1, Wh1T, xt1, nullptr, nullptr, MALL, 512, 128, 128);
    row_att<4><<<NN, 64, 0, stream>>>(xt1, att1, 0, ax);
    row_att<4><<<MME, 64, 0, stream>>>(xt1 + (size_t)NN*512, att1, 128, ae);
    seg_softmax<4><<<MME, 128, 0, stream>>>(eoffb, eperm, he_n, ax, ae, alpha);
    seg_eo<4><<<MME, 128, 0, stream>>>(eoffb, eperm, he_n, alpha, xt1, eo);
    seg_node_out<4><<<NN, 128, 0, stream>>>(noffb, nperm, he_e, alpha, eo, hall1, bh1, hall2);
    zero_f<<<1, 256, 0, stream>>>(stats, 256);
    bn_stats<<<128, 256, 0, stream>>>(hall2, stats, NN);
    bn_finalize<<<1, 128, 0, stream>>>(stats, g2, be2, 1.f/NN);
    bn_apply4<<<1024, 256, 0, stream>>>((float4*)hall2, stats, (size_t)NN*32);

    // ---- hconv2 (heads=1) ----
    seg_sum_edge<<<MME, 128, 0, stream>>>(eoffb, eperm, he_n, hall2, hall2 + (size_t)NN*128);
    gemm_mfma<0><<<dim3(1, MALL/128, 1), 256, 0, stream>>>(hall2, Wh2T, xt2, nullptr, nullptr, MALL, 128, 128, 128);
    row_att<1><<<NN, 64, 0, stream>>>(xt2, att2, 0, ax);
    row_att<1><<<MME, 64, 0, stream>>>(xt2 + (size_t)NN*128, att2, 128, ae);
    seg_softmax<1><<<MME, 128, 0, stream>>>(eoffb, eperm, he_n, ax, ae, alpha);
    seg_eo<1><<<MME, 128, 0, stream>>>(eoffb, eperm, he_n, alpha, xt2, eo);
    seg_node_out<1><<<NN, 128, 0, stream>>>(noffb, nperm, he_e, alpha, eo, hall2, bh2, h3);
    zero_f<<<1, 256, 0, stream>>>(stats, 256);
    bn_stats<<<128, 256, 0, stream>>>(h3, stats, NN);
    bn_finalize<<<1, 128, 0, stream>>>(stats, g3, be3, 1.f/NN);
    bn_apply4<<<1024, 256, 0, stream>>>((float4*)h3, stats, (size_t)NN*32);

    // ---- final: out = BN4(x + lrelu(h3 @ W3 + b3)) ----
    gemm_mfma<2><<<dim3(DIN/128, NN/128, 1), 256, 0, stream>>>(h3, W3T, out, b3, x, NN, DIN, 128, 128);
    zero_f<<<1, 256, 0, stream>>>(stats, 256);
    bn_stats<<<1024, 256, 0, stream>>>(out, stats, NN*TT);
    bn_finalize<<<1, 128, 0, stream>>>(stats, g4, be4, 1.f/((float)NN*TT));
    bn_apply4<<<2048, 256, 0, stream>>>((float4*)out, stats, (size_t)NN*TT*32);
}

// Round 3
// 532.926 us; speedup vs baseline: 1.5999x; 1.0891x over previous
//
#include <hip/hip_runtime.h>
#include <hip/hip_bf16.h>
#include <math.h>

#define NN   8192
#define TT   32
#define DIN  4096
#define MME  1024
#define NNZK 131072
#define EPSV 1e-5f
#define MALL (NN + MME)   // 9216 combined node+edge rows

typedef __attribute__((ext_vector_type(8))) short bf16x8;
typedef __attribute__((ext_vector_type(4))) float f32x4;

__device__ __forceinline__ float lrelu(float v){ return v > 0.f ? v : 0.2f*v; }
__device__ __forceinline__ short f2b(float f){
    union { __hip_bfloat16 h; short s; } u; u.h = __float2bfloat16(f); return u.s;
}

// ---------------------------------------------------------------- utilities
__global__ void zero_i(int* p, int n){ int i = blockIdx.x*256 + threadIdx.x; if (i < n) p[i] = 0; }
__global__ void zero_f(float* p, int n){ int i = blockIdx.x*256 + threadIdx.x; if (i < n) p[i] = 0.f; }
__global__ void copy_i(const int* a, int* b, int n){ int i = blockIdx.x*256 + threadIdx.x; if (i < n) b[i] = a[i]; }

__global__ void count_seg(const int* __restrict__ he_n, const int* __restrict__ he_e,
                          int* __restrict__ ncnt, int* __restrict__ ecnt){
    int k = blockIdx.x*256 + threadIdx.x;
    if (k < NNZK){ atomicAdd(&ecnt[he_e[k]], 1); atomicAdd(&ncnt[he_n[k]], 1); }
}

__global__ void scan_excl(const int* __restrict__ cnt, int* __restrict__ off, int n){
    __shared__ int buf[1024];
    __shared__ int carry;
    int t = threadIdx.x;
    if (t == 0) carry = 0;
    __syncthreads();
    for (int base = 0; base < n; base += 1024){
        int i = base + t;
        int v = (i < n) ? cnt[i] : 0;
        buf[t] = v; __syncthreads();
        for (int s = 1; s < 1024; s <<= 1){
            int tmp = (t >= s) ? buf[t - s] : 0;
            __syncthreads();
            buf[t] += tmp;
            __syncthreads();
        }
        if (i < n) off[i] = carry + buf[t] - v;
        __syncthreads();
        if (t == 1023) carry += buf[1023];
        __syncthreads();
    }
    if (t == 0) off[n] = carry;
}

__global__ void fill_perm(const int* __restrict__ seg, int* __restrict__ cur, int* __restrict__ perm){
    int k = blockIdx.x*256 + threadIdx.x;
    if (k < NNZK){ int p = atomicAdd(&cur[seg[k]], 1); perm[p] = k; }
}

// ------------------------------------------------ weight convert + transpose
__global__ void wconv_t(const float* __restrict__ W, __hip_bfloat16* __restrict__ BT, int K, int N){
    __shared__ float tile[32][33];
    int k0 = blockIdx.y*32, n0 = blockIdx.x*32;
    int tx = threadIdx.x & 31, ty = threadIdx.x >> 5;
    for (int i = ty; i < 32; i += 8) tile[i][tx] = W[(size_t)(k0+i)*N + n0+tx];
    __syncthreads();
    for (int i = ty; i < 32; i += 8)
        BT[(size_t)(n0+i)*K + k0 + tx] = __float2bfloat16(tile[tx][i]);
}

// ---------------------------------------------------------------- MFMA GEMM
// C[M,N] = A_fp32[M,K] @ B, with B given as BT_bf16[N,K] (K-major).
// EPI 0: plain store (split-K partial slice via blockIdx.z)
// EPI 2: C = lrelu(AB + bias[col]) + add[row,col], fused per-channel BN stats
#define SWZ(b) ((b) ^ ((((b) >> 6) & 7) << 4))

template<int EPI>
__global__ __launch_bounds__(256) void gemm_mfma(
    const float* __restrict__ A, const __hip_bfloat16* __restrict__ BT,
    float* __restrict__ C, const float* __restrict__ bias, const float* __restrict__ add,
    float* __restrict__ slots, int M, int N, int K, int kchunk)
{
    __shared__ f32x4 AsRaw[512];   // 8 KB
    __shared__ f32x4 BsRaw[512];   // 8 KB
    char* As = (char*)AsRaw;
    char* Bs = (char*)BsRaw;
    const int tid = threadIdx.x;
    const int lane = tid & 63;
    const int w = tid >> 6;
    const int m0 = blockIdx.y << 7, n0 = blockIdx.x << 7;
    const int kz = blockIdx.z * kchunk;
    const int wr = (w >> 1) << 6, wc = (w & 1) << 6;

    const int s0 = tid, s1 = tid + 256;
    const int r0 = s0 >> 2, k0b = (s0 & 3) << 3;
    const int r1 = s1 >> 2, k1b = (s1 & 3) << 3;
    const float* pA0 = A + (size_t)(m0 + r0)*K + kz + k0b;
    const float* pA1 = A + (size_t)(m0 + r1)*K + kz + k1b;
    const __hip_bfloat16* pB0 = BT + (size_t)(n0 + r0)*K + kz + k0b;
    const __hip_bfloat16* pB1 = BT + (size_t)(n0 + r1)*K + kz + k1b;
    const int wo0 = SWZ(s0 << 4), wo1 = SWZ(s1 << 4);

    int raOff[4], rbOff[4];
#pragma unroll
    for (int f = 0; f < 4; f++){
        int rowA = wr + f*16 + (lane & 15);
        raOff[f] = SWZ(rowA*64 + ((lane >> 4) << 4));
        int rowB = wc + f*16 + (lane & 15);
        rbOff[f] = SWZ(rowB*64 + ((lane >> 4) << 4));
    }

    f32x4 acc[4][4] = {};

    float4 a0l = *(const float4*)pA0, a0h = *(const float4*)(pA0+4);
    float4 a1l = *(const float4*)pA1, a1h = *(const float4*)(pA1+4);
    bf16x8 b0 = *(const bf16x8*)pB0, b1 = *(const bf16x8*)pB1;

    const int nsteps = kchunk >> 5;
    for (int ks = 0; ks < nsteps; ks++){
        bf16x8 va0, va1;
        va0[0]=f2b(a0l.x); va0[1]=f2b(a0l.y); va0[2]=f2b(a0l.z); va0[3]=f2b(a0l.w);
        va0[4]=f2b(a0h.x); va0[5]=f2b(a0h.y); va0[6]=f2b(a0h.z); va0[7]=f2b(a0h.w);
        va1[0]=f2b(a1l.x); va1[1]=f2b(a1l.y); va1[2]=f2b(a1l.z); va1[3]=f2b(a1l.w);
        va1[4]=f2b(a1h.x); va1[5]=f2b(a1h.y); va1[6]=f2b(a1h.z); va1[7]=f2b(a1h.w);
        __syncthreads();
        *(bf16x8*)(As + wo0) = va0;
        *(bf16x8*)(As + wo1) = va1;
        *(bf16x8*)(Bs + wo0) = b0;
        *(bf16x8*)(Bs + wo1) = b1;
        __syncthreads();
        if (ks + 1 < nsteps){
            pA0 += 32; pA1 += 32; pB0 += 32; pB1 += 32;
            a0l = *(const float4*)pA0; a0h = *(const float4*)(pA0+4);
            a1l = *(const float4*)pA1; a1h = *(const float4*)(pA1+4);
            b0 = *(const bf16x8*)pB0;  b1 = *(const bf16x8*)pB1;
        }
        bf16x8 af[4], bfr[4];
#pragma unroll
        for (int f = 0; f < 4; f++){
            af[f]  = *(const bf16x8*)(As + raOff[f]);
            bfr[f] = *(const bf16x8*)(Bs + rbOff[f]);
        }
#pragma unroll
        for (int mf = 0; mf < 4; mf++)
#pragma unroll
            for (int nf = 0; nf < 4; nf++)
                acc[mf][nf] = __builtin_amdgcn_mfma_f32_16x16x32_bf16(af[mf], bfr[nf], acc[mf][nf], 0, 0, 0);
    }

    if (EPI == 2){
        __shared__ float sS[128], sQ[128];
        if (tid < 128){ sS[tid] = 0.f; sQ[tid] = 0.f; }
        __syncthreads();
#pragma unroll
        for (int nf = 0; nf < 4; nf++){
            int lc = wc + nf*16 + (lane & 15);
            int col = n0 + lc;
            float bv = bias[col];
            float s = 0.f, q = 0.f;
#pragma unroll
            for (int mf = 0; mf < 4; mf++){
#pragma unroll
                for (int r = 0; r < 4; r++){
                    int row = m0 + wr + mf*16 + ((lane >> 4) << 2) + r;
                    float v = acc[mf][nf][r] + bv;
                    v = lrelu(v);
                    v += add[(size_t)row*N + col];
                    C[(size_t)row*N + col] = v;
                    s += v; q += v*v;
                }
            }
            atomicAdd(&sS[lc], s);
            atomicAdd(&sQ[lc], q);
        }
        __syncthreads();
        if (tid < 128){
            atomicAdd(&slots[blockIdx.x*256 + tid], sS[tid]);
            atomicAdd(&slots[blockIdx.x*256 + 128 + tid], sQ[tid]);
        }
    } else {
        float* Cz = C + (size_t)blockIdx.z * ((size_t)M * (size_t)N);
#pragma unroll
        for (int mf = 0; mf < 4; mf++){
#pragma unroll
            for (int nf = 0; nf < 4; nf++){
                int col = n0 + wc + nf*16 + (lane & 15);
#pragma unroll
                for (int r = 0; r < 4; r++){
                    int row = m0 + wr + mf*16 + ((lane >> 4) << 2) + r;
                    Cz[(size_t)row*N + col] = acc[mf][nf][r];
                }
            }
        }
    }
}

// split-K reduce + bias + lrelu + fused BN stats (row length 128 floats)
__global__ void reduce8s(const float* __restrict__ part, const float* __restrict__ bias,
                         float* __restrict__ out, int nf4, int parts, float* __restrict__ slots){
    int tid = threadIdx.x;
    int i = blockIdx.x*256 + tid;           // grid sized exactly: nf4 == grid*256
    float4 s = ((const float4*)part)[i];
    for (int z = 1; z < parts; z++){
        float4 p = ((const float4*)part)[(size_t)z*nf4 + i];
        s.x += p.x; s.y += p.y; s.z += p.z; s.w += p.w;
    }
    int c0 = (i & 31) << 2;
    s.x = lrelu(s.x + bias[c0+0]); s.y = lrelu(s.y + bias[c0+1]);
    s.z = lrelu(s.z + bias[c0+2]); s.w = lrelu(s.w + bias[c0+3]);
    ((float4*)out)[i] = s;
    __shared__ float S[128], Q[128];
    if (tid < 128){ S[tid] = 0.f; Q[tid] = 0.f; }
    __syncthreads();
    atomicAdd(&S[c0+0], s.x); atomicAdd(&Q[c0+0], s.x*s.x);
    atomicAdd(&S[c0+1], s.y); atomicAdd(&Q[c0+1], s.y*s.y);
    atomicAdd(&S[c0+2], s.z); atomicAdd(&Q[c0+2], s.z*s.z);
    atomicAdd(&S[c0+3], s.w); atomicAdd(&Q[c0+3], s.w*s.w);
    __syncthreads();
    if (tid < 128){
        int slot = blockIdx.x & 31;
        atomicAdd(&slots[slot*256 + tid], S[tid]);
        atomicAdd(&slots[slot*256 + 128 + tid], Q[tid]);
    }
}

// ---------------------------------------------------------------- BatchNorm
// vectorized stats: float4 loads, fixed thread->channel-group mapping
__global__ void bn_stats_v2(const float* __restrict__ x, float* __restrict__ slots, int rows){
    int cg = threadIdx.x & 31, rg = threadIdx.x >> 5;
    float4 s = {0,0,0,0}, q = {0,0,0,0};
    for (int r = blockIdx.x*8 + rg; r < rows; r += gridDim.x*8){
        float4 v = ((const float4*)x)[(size_t)r*32 + cg];
        s.x += v.x; q.x += v.x*v.x;
        s.y += v.y; q.y += v.y*v.y;
        s.z += v.z; q.z += v.z*v.z;
        s.w += v.w; q.w += v.w*v.w;
    }
    __shared__ float S[128], Q[128];
    if (threadIdx.x < 128){ S[threadIdx.x] = 0.f; Q[threadIdx.x] = 0.f; }
    __syncthreads();
    int c0 = cg << 2;
    atomicAdd(&S[c0+0], s.x); atomicAdd(&Q[c0+0], q.x);
    atomicAdd(&S[c0+1], s.y); atomicAdd(&Q[c0+1], q.y);
    atomicAdd(&S[c0+2], s.z); atomicAdd(&Q[c0+2], q.z);
    atomicAdd(&S[c0+3], s.w); atomicAdd(&Q[c0+3], q.w);
    __syncthreads();
    if (threadIdx.x < 128){
        int slot = blockIdx.x & 31;
        atomicAdd(&slots[slot*256 + threadIdx.x], S[threadIdx.x]);
        atomicAdd(&slots[slot*256 + 128 + threadIdx.x], Q[threadIdx.x]);
    }
}

__global__ void bn_finalize2(const float* __restrict__ slots, int nslots,
                             const float* __restrict__ g, const float* __restrict__ b,
                             float invR, float* __restrict__ coef){
    int c = threadIdx.x;
    float s = 0.f, q = 0.f;
    for (int k = 0; k < nslots; k++){ s += slots[k*256 + c]; q += slots[k*256 + 128 + c]; }
    float m = s*invR;
    float v = q*invR - m*m;
    float sc = g[c]*rsqrtf(v + EPSV);
    coef[c] = sc;
    coef[128 + c] = b[c] - m*sc;
}

__global__ void bn_apply4(float4* __restrict__ x, const float* __restrict__ coef, size_t n4){
    size_t i = (size_t)blockIdx.x*blockDim.x + threadIdx.x;
    size_t stride = (size_t)gridDim.x*blockDim.x;
    for (; i < n4; i += stride){
        int c0 = (int)(i & 31) * 4;
        float4 v = x[i];
        v.x = v.x*coef[c0+0] + coef[128+c0+0];
        v.y = v.y*coef[c0+1] + coef[128+c0+1];
        v.z = v.z*coef[c0+2] + coef[128+c0+2];
        v.w = v.w*coef[c0+3] + coef[128+c0+3];
        x[i] = v;
    }
}

// ---------------------------------------------------------------- segment ops
__global__ void seg_sum_edge(const int* __restrict__ eoff, const int* __restrict__ eperm,
                             const int* __restrict__ he_n, const float* __restrict__ h,
                             float* __restrict__ out){
    int m = blockIdx.x, c = threadIdx.x;
    int s0 = eoff[m], cnt = eoff[m+1] - s0;
    __shared__ int sn[128];
    float acc = 0.f;
    for (int base = 0; base < cnt; base += 128){
        int i = base + c;
        if (i < cnt) sn[c] = he_n[eperm[s0+i]];
        __syncthreads();
        int lim = min(128, cnt - base);
        for (int j = 0; j < lim; j++) acc += h[(size_t)sn[j]*128 + c];
        __syncthreads();
    }
    out[(size_t)m*128 + c] = acc;
}

template<int H>
__global__ void row_att(const float* __restrict__ xt, const float* __restrict__ att,
                        int aoff, float* __restrict__ out){
    int n = blockIdx.x, lane = threadIdx.x;
#pragma unroll
    for (int h = 0; h < H; h++){
        const float* xr = xt + (size_t)n*(H*128) + h*128;
        const float* ar = att + h*256 + aoff;
        float s = xr[lane]*ar[lane] + xr[lane+64]*ar[lane+64];
        for (int d = 32; d > 0; d >>= 1) s += __shfl_down(s, d);
        if (lane == 0) out[n*H + h] = s;
    }
}

template<int H>
__global__ void seg_softmax(const int* __restrict__ eoff, const int* __restrict__ eperm,
                            const int* __restrict__ he_n,
                            const float* __restrict__ ax, const float* __restrict__ ae,
                            float* __restrict__ alpha){
    int m = blockIdx.x, t = threadIdx.x;
    int s0 = eoff[m], cnt = eoff[m+1] - s0;
    if (cnt == 0) return;
    __shared__ float red[128];
    float aeh[H];
#pragma unroll
    for (int h = 0; h < H; h++) aeh[h] = ae[m*H + h];
    float lmax[H];
#pragma unroll
    for (int h = 0; h < H; h++) lmax[h] = -1e30f;
    for (int i = t; i < cnt; i += 128){
        int k = eperm[s0+i]; int n = he_n[k];
#pragma unroll
        for (int h = 0; h < H; h++){
            float v = lrelu(ax[n*H + h] + aeh[h]);
            alpha[(size_t)k*H + h] = v;
            lmax[h] = fmaxf(lmax[h], v);
        }
    }
    float gmax[H];
#pragma unroll
    for (int h = 0; h < H; h++){
        red[t] = lmax[h]; __syncthreads();
        for (int s = 64; s > 0; s >>= 1){ if (t < s) red[t] = fmaxf(red[t], red[t+s]); __syncthreads(); }
        gmax[h] = red[0]; __syncthreads();
    }
    float lsum[H];
#pragma unroll
    for (int h = 0; h < H; h++) lsum[h] = 0.f;
    for (int i = t; i < cnt; i += 128){
        int k = eperm[s0+i];
#pragma unroll
        for (int h = 0; h < H; h++){
            float ex = __expf(alpha[(size_t)k*H + h] - gmax[h]);
            alpha[(size_t)k*H + h] = ex;
            lsum[h] += ex;
        }
    }
    float ginv[H];
#pragma unroll
    for (int h = 0; h < H; h++){
        red[t] = lsum[h]; __syncthreads();
        for (int s = 64; s > 0; s >>= 1){ if (t < s) red[t] += red[t+s]; __syncthreads(); }
        ginv[h] = 1.f/red[0]; __syncthreads();
    }
    for (int i = t; i < cnt; i += 128){
        int k = eperm[s0+i];
#pragma unroll
        for (int h = 0; h < H; h++) alpha[(size_t)k*H + h] *= ginv[h];
    }
}

// heads=4, 256 threads: thread handles heads {hb, hb+2} for channel c
__global__ void seg_eo4(const int* __restrict__ eoff, const int* __restrict__ eperm,
                        const int* __restrict__ he_n,
                        const float* __restrict__ alpha, const float* __restrict__ xt,
                        float* __restrict__ eo){
    int m = blockIdx.x;
    int c = threadIdx.x & 127, hb = threadIdx.x >> 7;   // hb in {0,1}
    int s0 = eoff[m], cnt = eoff[m+1] - s0;
    __shared__ int sn[128];
    __shared__ float sa[128][4];
    float acc0 = 0.f, acc1 = 0.f;
    for (int base = 0; base < cnt; base += 128){
        int i = base + threadIdx.x;
        if (threadIdx.x < 128 && i < cnt){
            int k = eperm[s0+i];
            sn[threadIdx.x] = he_n[k];
#pragma unroll
            for (int h = 0; h < 4; h++) sa[threadIdx.x][h] = alpha[(size_t)k*4 + h];
        }
        __syncthreads();
        int lim = min(128, cnt - base);
        for (int j = 0; j < lim; j++){
            const float* xr = xt + (size_t)sn[j]*512;
            acc0 += sa[j][hb]   * xr[hb*128 + c];
            acc1 += sa[j][hb+2] * xr[(hb+2)*128 + c];
        }
        __syncthreads();
    }
    float binv = cnt > 0 ? 1.f/(float)cnt : 0.f;
    eo[(size_t)m*512 + hb*128 + c]     = acc0*binv;
    eo[(size_t)m*512 + (hb+2)*128 + c] = acc1*binv;
}

__global__ void seg_eo1(const int* __restrict__ eoff, const int* __restrict__ eperm,
                        const int* __restrict__ he_n,
                        const float* __restrict__ alpha, const float* __restrict__ xt,
                        float* __restrict__ eo){
    int m = blockIdx.x, c = threadIdx.x;
    int s0 = eoff[m], cnt = eoff[m+1] - s0;
    __shared__ int sn[128];
    __shared__ float sa[128];
    float acc = 0.f;
    for (int base = 0; base < cnt; base += 128){
        int i = base + c;
        if (i < cnt){
            int k = eperm[s0+i];
            sn[c] = he_n[k];
            sa[c] = alpha[k];
        }
        __syncthreads();
        int lim = min(128, cnt - base);
        for (int j = 0; j < lim; j++) acc += sa[j]*xt[(size_t)sn[j]*128 + c];
        __syncthreads();
    }
    float binv = cnt > 0 ? 1.f/(float)cnt : 0.f;
    eo[(size_t)m*128 + c] = acc*binv;
}

template<int H>
__global__ void seg_node_out(const int* __restrict__ noff, const int* __restrict__ nperm,
                             const int* __restrict__ he_e,
                             const float* __restrict__ alpha, const float* __restrict__ eo,
                             const float* __restrict__ hin, const float* __restrict__ bias,
                             float* __restrict__ hout){
    int n = blockIdx.x, c = threadIdx.x;
    int s0 = noff[n], cnt = noff[n+1] - s0;
    float acc = 0.f;
    for (int i = 0; i < cnt; i++){
        int k = nperm[s0+i]; int e = he_e[k];
        const float* er = eo + (size_t)e*(128*H);
#pragma unroll
        for (int h = 0; h < H; h++) acc += alpha[(size_t)k*H + h]*er[h*128 + c];
    }
    float dinv = cnt > 0 ? 1.f/((float)cnt*(float)H) : 0.f;
    hout[(size_t)n*128 + c] = hin[(size_t)n*128 + c] + bias[c] + acc*dinv;
}

// ---------------------------------------------------------------- launcher
extern "C" void kernel_launch(void* const* d_in, const int* in_sizes, int n_in,
                              void* d_out, int out_size, void* d_ws, size_t ws_size,
                              hipStream_t stream){
    const float* x    = (const float*)d_in[0];
    const int*   he_n = (const int*)  d_in[1];
    const int*   he_e = (const int*)  d_in[2];
    const float* W1   = (const float*)d_in[3];
    const float* b1   = (const float*)d_in[4];
    const float* g1   = (const float*)d_in[5];
    const float* be1  = (const float*)d_in[6];
    const float* Wh1  = (const float*)d_in[7];
    const float* att1 = (const float*)d_in[8];
    const float* bh1  = (const float*)d_in[9];
    const float* g2   = (const float*)d_in[10];
    const float* be2  = (const float*)d_in[11];
    const float* Wh2  = (const float*)d_in[12];
    const float* att2 = (const float*)d_in[13];
    const float* bh2  = (const float*)d_in[14];
    const float* g3   = (const float*)d_in[15];
    const float* be3  = (const float*)d_in[16];
    const float* W3   = (const float*)d_in[17];
    const float* b3   = (const float*)d_in[18];
    const float* g4   = (const float*)d_in[19];
    const float* be4  = (const float*)d_in[20];
    float* out = (float*)d_out;

    char* ws = (char*)d_ws;
    size_t off = 0;
    auto alloc = [&](size_t bytes)->char*{ char* p = ws + off; off += (bytes + 255) & ~(size_t)255; return p; };

    float* hall1  = (float*)alloc((size_t)MALL*128*4);
    float* hall2  = (float*)alloc((size_t)MALL*128*4);
    float* h3     = (float*)alloc((size_t)NN*128*4);
    float* xt1    = (float*)alloc((size_t)MALL*512*4);
    float* xt2    = (float*)alloc((size_t)MALL*128*4);
    float* eo     = (float*)alloc((size_t)MME*512*4);
    float* alpha  = (float*)alloc((size_t)NNZK*4*4);
    float* ax     = (float*)alloc((size_t)NN*4*4);
    float* ae     = (float*)alloc((size_t)MME*4*4);
    float* slots  = (float*)alloc((size_t)32*256*4);
    float* coef   = (float*)alloc(256*4);
    float* part   = (float*)alloc((size_t)8*NN*128*4);
    __hip_bfloat16* W1T  = (__hip_bfloat16*)alloc((size_t)128*DIN*2);
    __hip_bfloat16* Wh1T = (__hip_bfloat16*)alloc((size_t)512*128*2);
    __hip_bfloat16* Wh2T = (__hip_bfloat16*)alloc((size_t)128*128*2);
    __hip_bfloat16* W3T  = (__hip_bfloat16*)alloc((size_t)DIN*128*2);
    int* ecnt  = (int*)alloc(MME*4);
    int* eoffb = (int*)alloc((MME+1)*4);
    int* ecur  = (int*)alloc(MME*4);
    int* ncnt  = (int*)alloc(NN*4);
    int* noffb = (int*)alloc((NN+1)*4);
    int* ncur  = (int*)alloc(NN*4);
    int* eperm = (int*)alloc((size_t)NNZK*4);
    int* nperm = (int*)alloc((size_t)NNZK*4);

    // ---- CSR build ----
    zero_i<<<(MME+255)/256, 256, 0, stream>>>(ecnt, MME);
    zero_i<<<(NN+255)/256, 256, 0, stream>>>(ncnt, NN);
    count_seg<<<NNZK/256, 256, 0, stream>>>(he_n, he_e, ncnt, ecnt);
    scan_excl<<<1, 1024, 0, stream>>>(ecnt, eoffb, MME);
    scan_excl<<<1, 1024, 0, stream>>>(ncnt, noffb, NN);
    copy_i<<<(MME+255)/256, 256, 0, stream>>>(eoffb, ecur, MME);
    copy_i<<<(NN+255)/256, 256, 0, stream>>>(noffb, ncur, NN);
    fill_perm<<<NNZK/256, 256, 0, stream>>>(he_e, ecur, eperm);
    fill_perm<<<NNZK/256, 256, 0, stream>>>(he_n, ncur, nperm);

    // ---- weight transpose+convert ----
    wconv_t<<<dim3(128/32, DIN/32), 256, 0, stream>>>(W1,  W1T,  DIN, 128);
    wconv_t<<<dim3(512/32, 128/32), 256, 0, stream>>>(Wh1, Wh1T, 128, 512);
    wconv_t<<<dim3(128/32, 128/32), 256, 0, stream>>>(Wh2, Wh2T, 128, 128);
    wconv_t<<<dim3(DIN/32, 128/32), 256, 0, stream>>>(W3,  W3T,  128, DIN);

    // ---- layer 0: h1 = lrelu(x @ W1 + b1); BN1 (stats fused in reduce8s) ----
    gemm_mfma<0><<<dim3(1, NN/128, 8), 256, 0, stream>>>(x, W1T, part, nullptr, nullptr, nullptr, NN, 128, DIN, DIN/8);
    zero_f<<<32, 256, 0, stream>>>(slots, 32*256);
    reduce8s<<<NN*128/4/256, 256, 0, stream>>>(part, b1, hall1, NN*128/4, 8, slots);
    bn_finalize2<<<1, 128, 0, stream>>>(slots, 32, g1, be1, 1.f/NN, coef);
    bn_apply4<<<1024, 256, 0, stream>>>((float4*)hall1, coef, (size_t)NN*32);

    // ---- hconv1 (heads=4) ----
    seg_sum_edge<<<MME, 128, 0, stream>>>(eoffb, eperm, he_n, hall1, hall1 + (size_t)NN*128);
    gemm_mfma<0><<<dim3(512/128, MALL/128, 1), 256, 0, stream>>>(hall1, Wh1T, xt1, nullptr, nullptr, nullptr, MALL, 512, 128, 128);
    row_att<4><<<NN, 64, 0, stream>>>(xt1, att1, 0, ax);
    row_att<4><<<MME, 64, 0, stream>>>(xt1 + (size_t)NN*512, att1, 128, ae);
    seg_softmax<4><<<MME, 128, 0, stream>>>(eoffb, eperm, he_n, ax, ae, alpha);
    seg_eo4<<<MME, 256, 0, stream>>>(eoffb, eperm, he_n, alpha, xt1, eo);
    seg_node_out<4><<<NN, 128, 0, stream>>>(noffb, nperm, he_e, alpha, eo, hall1, bh1, hall2);
    zero_f<<<32, 256, 0, stream>>>(slots, 32*256);
    bn_stats_v2<<<256, 256, 0, stream>>>(hall2, slots, NN);
    bn_finalize2<<<1, 128, 0, stream>>>(slots, 32, g2, be2, 1.f/NN, coef);
    bn_apply4<<<1024, 256, 0, stream>>>((float4*)hall2, coef, (size_t)NN*32);

    // ---- hconv2 (heads=1) ----
    seg_sum_edge<<<MME, 128, 0, stream>>>(eoffb, eperm, he_n, hall2, hall2 + (size_t)NN*128);
    gemm_mfma<0><<<dim3(1, MALL/128, 1), 256, 0, stream>>>(hall2, Wh2T, xt2, nullptr, nullptr, nullptr, MALL, 128, 128, 128);
    row_att<1><<<NN, 64, 0, stream>>>(xt2, att2, 0, ax);
    row_att<1><<<MME, 64, 0, stream>>>(xt2 + (size_t)NN*128, att2, 128, ae);
    seg_softmax<1><<<MME, 128, 0, stream>>>(eoffb, eperm, he_n, ax, ae, alpha);
    seg_eo1<<<MME, 128, 0, stream>>>(eoffb, eperm, he_n, alpha, xt2, eo);
    seg_node_out<1><<<NN, 128, 0, stream>>>(noffb, nperm, he_e, alpha, eo, hall2, bh2, h3);
    zero_f<<<32, 256, 0, stream>>>(slots, 32*256);
    bn_stats_v2<<<256, 256, 0, stream>>>(h3, slots, NN);
    bn_finalize2<<<1, 128, 0, stream>>>(slots, 32, g3, be3, 1.f/NN, coef);
    bn_apply4<<<1024, 256, 0, stream>>>((float4*)h3, coef, (size_t)NN*32);

    // ---- final: out = BN4(x + lrelu(h3 @ W3 + b3)), stats fused in GEMM3 ----
    zero_f<<<32, 256, 0, stream>>>(slots, 32*256);
    gemm_mfma<2><<<dim3(DIN/128, NN/128, 1), 256, 0, stream>>>(h3, W3T, out, b3, x, slots, NN, DIN, 128, 128);
    bn_finalize2<<<1, 128, 0, stream>>>(slots, 32, g4, be4, 1.f/((float)NN*TT), coef);
    bn_apply4<<<4096, 256, 0, stream>>>((float4*)out, coef, (size_t)NN*TT*32);
}

// Round 4
// 526.717 us; speedup vs baseline: 1.6188x; 1.0118x over previous
//
#include <hip/hip_runtime.h>
#include <hip/hip_bf16.h>
#include <math.h>

#define NN   8192
#define TT   32
#define DIN  4096
#define MME  1024
#define NNZK 131072
#define EPSV 1e-5f
#define MALL (NN + MME)   // 9216 combined node+edge rows

typedef __attribute__((ext_vector_type(8))) short bf16x8;
typedef __attribute__((ext_vector_type(4))) float f32x4;

__device__ __forceinline__ float lrelu(float v){ return v > 0.f ? v : 0.2f*v; }
__device__ __forceinline__ short f2b(float f){
    union { __hip_bfloat16 h; short s; } u; u.h = __float2bfloat16(f); return u.s;
}

// ---------------------------------------------------------------- utilities
__global__ void zero_i(int* p, int n){ int i = blockIdx.x*256 + threadIdx.x; if (i < n) p[i] = 0; }
__global__ void zero_f(float* p, int n){ int i = blockIdx.x*256 + threadIdx.x; if (i < n) p[i] = 0.f; }
__global__ void copy_i(const int* a, int* b, int n){ int i = blockIdx.x*256 + threadIdx.x; if (i < n) b[i] = a[i]; }

__global__ void count_seg(const int* __restrict__ he_n, const int* __restrict__ he_e,
                          int* __restrict__ ncnt, int* __restrict__ ecnt){
    int k = blockIdx.x*256 + threadIdx.x;
    if (k < NNZK){ atomicAdd(&ecnt[he_e[k]], 1); atomicAdd(&ncnt[he_n[k]], 1); }
}

__global__ void scan_excl(const int* __restrict__ cnt, int* __restrict__ off, int n){
    __shared__ int buf[1024];
    __shared__ int carry;
    int t = threadIdx.x;
    if (t == 0) carry = 0;
    __syncthreads();
    for (int base = 0; base < n; base += 1024){
        int i = base + t;
        int v = (i < n) ? cnt[i] : 0;
        buf[t] = v; __syncthreads();
        for (int s = 1; s < 1024; s <<= 1){
            int tmp = (t >= s) ? buf[t - s] : 0;
            __syncthreads();
            buf[t] += tmp;
            __syncthreads();
        }
        if (i < n) off[i] = carry + buf[t] - v;
        __syncthreads();
        if (t == 1023) carry += buf[1023];
        __syncthreads();
    }
    if (t == 0) off[n] = carry;
}

__global__ void fill_perm(const int* __restrict__ seg, int* __restrict__ cur, int* __restrict__ perm){
    int k = blockIdx.x*256 + threadIdx.x;
    if (k < NNZK){ int p = atomicAdd(&cur[seg[k]], 1); perm[p] = k; }
}

// ------------------------------------------------ weight convert + transpose
__global__ void wconv_t(const float* __restrict__ W, __hip_bfloat16* __restrict__ BT, int K, int N){
    __shared__ float tile[32][33];
    int k0 = blockIdx.y*32, n0 = blockIdx.x*32;
    int tx = threadIdx.x & 31, ty = threadIdx.x >> 5;
    for (int i = ty; i < 32; i += 8) tile[i][tx] = W[(size_t)(k0+i)*N + n0+tx];
    __syncthreads();
    for (int i = ty; i < 32; i += 8)
        BT[(size_t)(n0+i)*K + k0 + tx] = __float2bfloat16(tile[tx][i]);
}

#define SWZ(b) ((b) ^ ((((b) >> 6) & 7) << 4))

// ---------------------------------------------------------------- MFMA GEMM (swapped orientation)
// C[M,N] = Aact[M,K] @ Bwt^T, Bwt given as [N,K] bf16.
// Weight rows are the MFMA A-operand -> D "row" dim = N (fast axis) = (lane>>4)*4+r
// -> each lane's f32x4 acc covers 4 CONSECUTIVE output columns: float4 stores.
// MODE 0: plain store to split-K slice z
// MODE 1: v=lrelu(acc+bias4); v+=add4; v=v*sc4+sh4; store (BN apply fused)
template<int MODE>
__global__ __launch_bounds__(256) void gemm_nt(
    const float* __restrict__ Aact, const __hip_bfloat16* __restrict__ Bwt,
    float* __restrict__ C, const float* __restrict__ bias, const float* __restrict__ add,
    const float* __restrict__ coef, int M, int N, int K, int kchunk)
{
    __shared__ f32x4 WsRaw[512];   // 8 KB: weight tile 128(N) x 32(K) bf16
    __shared__ f32x4 XsRaw[512];   // 8 KB: act tile 128(M) x 32(K) bf16
    char* Ws = (char*)WsRaw;
    char* Xs = (char*)XsRaw;
    const int tid = threadIdx.x;
    const int lane = tid & 63;
    const int w = tid >> 6;
    const int m0 = blockIdx.y << 7, n0 = blockIdx.x << 7;
    const int kz = blockIdx.z * kchunk;
    const int wN = (w >> 1) << 6, wM = (w & 1) << 6;

    const int s0 = tid, s1 = tid + 256;
    const int r0 = s0 >> 2, k0b = (s0 & 3) << 3;
    const int r1 = s1 >> 2, k1b = (s1 & 3) << 3;
    const float* pX0 = Aact + (size_t)(m0 + r0)*K + kz + k0b;
    const float* pX1 = Aact + (size_t)(m0 + r1)*K + kz + k1b;
    const __hip_bfloat16* pW0 = Bwt + (size_t)(n0 + r0)*K + kz + k0b;
    const __hip_bfloat16* pW1 = Bwt + (size_t)(n0 + r1)*K + kz + k1b;
    const int wo0 = SWZ(s0 << 4), wo1 = SWZ(s1 << 4);

    int rwOff[4], rxOff[4];
#pragma unroll
    for (int f = 0; f < 4; f++){
        rwOff[f] = SWZ((wN + f*16 + (lane & 15))*64 + ((lane >> 4) << 4));
        rxOff[f] = SWZ((wM + f*16 + (lane & 15))*64 + ((lane >> 4) << 4));
    }

    f32x4 acc[4][4] = {};

    float4 x0l = *(const float4*)pX0, x0h = *(const float4*)(pX0+4);
    float4 x1l = *(const float4*)pX1, x1h = *(const float4*)(pX1+4);
    bf16x8 w0 = *(const bf16x8*)pW0, w1 = *(const bf16x8*)pW1;

    const int nsteps = kchunk >> 5;
    for (int ks = 0; ks < nsteps; ks++){
        bf16x8 vx0, vx1;
        vx0[0]=f2b(x0l.x); vx0[1]=f2b(x0l.y); vx0[2]=f2b(x0l.z); vx0[3]=f2b(x0l.w);
        vx0[4]=f2b(x0h.x); vx0[5]=f2b(x0h.y); vx0[6]=f2b(x0h.z); vx0[7]=f2b(x0h.w);
        vx1[0]=f2b(x1l.x); vx1[1]=f2b(x1l.y); vx1[2]=f2b(x1l.z); vx1[3]=f2b(x1l.w);
        vx1[4]=f2b(x1h.x); vx1[5]=f2b(x1h.y); vx1[6]=f2b(x1h.z); vx1[7]=f2b(x1h.w);
        __syncthreads();
        *(bf16x8*)(Xs + wo0) = vx0;
        *(bf16x8*)(Xs + wo1) = vx1;
        *(bf16x8*)(Ws + wo0) = w0;
        *(bf16x8*)(Ws + wo1) = w1;
        __syncthreads();
        if (ks + 1 < nsteps){
            pX0 += 32; pX1 += 32; pW0 += 32; pW1 += 32;
            x0l = *(const float4*)pX0; x0h = *(const float4*)(pX0+4);
            x1l = *(const float4*)pX1; x1h = *(const float4*)(pX1+4);
            w0 = *(const bf16x8*)pW0;  w1 = *(const bf16x8*)pW1;
        }
        bf16x8 wf[4], xf[4];
#pragma unroll
        for (int f = 0; f < 4; f++){
            wf[f] = *(const bf16x8*)(Ws + rwOff[f]);
            xf[f] = *(const bf16x8*)(Xs + rxOff[f]);
        }
#pragma unroll
        for (int i = 0; i < 4; i++)
#pragma unroll
            for (int j = 0; j < 4; j++)
                acc[i][j] = __builtin_amdgcn_mfma_f32_16x16x32_bf16(wf[i], xf[j], acc[i][j], 0, 0, 0);
    }

    const int mc = wM + (lane & 15);
    const int ncb = wN + ((lane >> 4) << 2);
    float* Cz = (MODE == 0) ? C + (size_t)blockIdx.z * ((size_t)M * (size_t)N) : C;
#pragma unroll
    for (int j = 0; j < 4; j++){
        int row = m0 + mc + j*16;
#pragma unroll
        for (int i = 0; i < 4; i++){
            int col = n0 + ncb + i*16;
            f32x4 v = acc[i][j];
            if (MODE == 1){
                float4 b4 = *(const float4*)&bias[col];
                v[0] = lrelu(v[0] + b4.x);
                v[1] = lrelu(v[1] + b4.y);
                v[2] = lrelu(v[2] + b4.z);
                v[3] = lrelu(v[3] + b4.w);
                float4 a4 = *(const float4*)&add[(size_t)row*N + col];
                int ch = (ncb + i*16) & 127;
                float4 sc = *(const float4*)&coef[ch];
                float4 sh = *(const float4*)&coef[128 + ch];
                v[0] = (v[0] + a4.x)*sc.x + sh.x;
                v[1] = (v[1] + a4.y)*sc.y + sh.y;
                v[2] = (v[2] + a4.z)*sc.z + sh.z;
                v[3] = (v[3] + a4.w)*sc.w + sh.w;
            }
            *(float4*)&Cz[(size_t)row*N + col] = *(float4*)&v;
        }
    }
}

// ---------------------------------------------------------------- stats-only GEMM (old orientation)
// computes y = lrelu(A@B^T + bias) + add, accumulates per-channel sum/sumsq; NO store.
__global__ __launch_bounds__(256) void gemm_stats(
    const float* __restrict__ A, const __hip_bfloat16* __restrict__ BT,
    const float* __restrict__ bias, const float* __restrict__ add,
    float* __restrict__ slots, int M, int N, int K, int kchunk)
{
    __shared__ f32x4 AsRaw[512];
    __shared__ f32x4 BsRaw[512];
    char* As = (char*)AsRaw;
    char* Bs = (char*)BsRaw;
    const int tid = threadIdx.x;
    const int lane = tid & 63;
    const int w = tid >> 6;
    const int m0 = blockIdx.y << 7, n0 = blockIdx.x << 7;
    const int wr = (w >> 1) << 6, wc = (w & 1) << 6;

    const int s0 = tid, s1 = tid + 256;
    const int r0 = s0 >> 2, k0b = (s0 & 3) << 3;
    const int r1 = s1 >> 2, k1b = (s1 & 3) << 3;
    const float* pA0 = A + (size_t)(m0 + r0)*K + k0b;
    const float* pA1 = A + (size_t)(m0 + r1)*K + k1b;
    const __hip_bfloat16* pB0 = BT + (size_t)(n0 + r0)*K + k0b;
    const __hip_bfloat16* pB1 = BT + (size_t)(n0 + r1)*K + k1b;
    const int wo0 = SWZ(s0 << 4), wo1 = SWZ(s1 << 4);

    int raOff[4], rbOff[4];
#pragma unroll
    for (int f = 0; f < 4; f++){
        raOff[f] = SWZ((wr + f*16 + (lane & 15))*64 + ((lane >> 4) << 4));
        rbOff[f] = SWZ((wc + f*16 + (lane & 15))*64 + ((lane >> 4) << 4));
    }

    f32x4 acc[4][4] = {};

    float4 a0l = *(const float4*)pA0, a0h = *(const float4*)(pA0+4);
    float4 a1l = *(const float4*)pA1, a1h = *(const float4*)(pA1+4);
    bf16x8 b0 = *(const bf16x8*)pB0, b1 = *(const bf16x8*)pB1;

    const int nsteps = kchunk >> 5;
    for (int ks = 0; ks < nsteps; ks++){
        bf16x8 va0, va1;
        va0[0]=f2b(a0l.x); va0[1]=f2b(a0l.y); va0[2]=f2b(a0l.z); va0[3]=f2b(a0l.w);
        va0[4]=f2b(a0h.x); va0[5]=f2b(a0h.y); va0[6]=f2b(a0h.z); va0[7]=f2b(a0h.w);
        va1[0]=f2b(a1l.x); va1[1]=f2b(a1l.y); va1[2]=f2b(a1l.z); va1[3]=f2b(a1l.w);
        va1[4]=f2b(a1h.x); va1[5]=f2b(a1h.y); va1[6]=f2b(a1h.z); va1[7]=f2b(a1h.w);
        __syncthreads();
        *(bf16x8*)(As + wo0) = va0;
        *(bf16x8*)(As + wo1) = va1;
        *(bf16x8*)(Bs + wo0) = b0;
        *(bf16x8*)(Bs + wo1) = b1;
        __syncthreads();
        if (ks + 1 < nsteps){
            pA0 += 32; pA1 += 32; pB0 += 32; pB1 += 32;
            a0l = *(const float4*)pA0; a0h = *(const float4*)(pA0+4);
            a1l = *(const float4*)pA1; a1h = *(const float4*)(pA1+4);
            b0 = *(const bf16x8*)pB0;  b1 = *(const bf16x8*)pB1;
        }
        bf16x8 af[4], bfr[4];
#pragma unroll
        for (int f = 0; f < 4; f++){
            af[f]  = *(const bf16x8*)(As + raOff[f]);
            bfr[f] = *(const bf16x8*)(Bs + rbOff[f]);
        }
#pragma unroll
        for (int mf = 0; mf < 4; mf++)
#pragma unroll
            for (int nf = 0; nf < 4; nf++)
                acc[mf][nf] = __builtin_amdgcn_mfma_f32_16x16x32_bf16(af[mf], bfr[nf], acc[mf][nf], 0, 0, 0);
    }

    __shared__ float sS[128], sQ[128];
    if (tid < 128){ sS[tid] = 0.f; sQ[tid] = 0.f; }
    __syncthreads();
#pragma unroll
    for (int nf = 0; nf < 4; nf++){
        int lc = wc + nf*16 + (lane & 15);
        int col = n0 + lc;
        float bv = bias[col];
        float s = 0.f, q = 0.f;
#pragma unroll
        for (int mf = 0; mf < 4; mf++){
#pragma unroll
            for (int r = 0; r < 4; r++){
                int row = m0 + wr + mf*16 + ((lane >> 4) << 2) + r;
                float v = lrelu(acc[mf][nf][r] + bv) + add[(size_t)row*N + col];
                s += v; q += v*v;
            }
        }
        atomicAdd(&sS[lc & 127], s);
        atomicAdd(&sQ[lc & 127], q);
    }
    __syncthreads();
    if (tid < 128){
        atomicAdd(&slots[(blockIdx.x & 31)*256 + tid], sS[tid]);
        atomicAdd(&slots[(blockIdx.x & 31)*256 + 128 + tid], sQ[tid]);
    }
}

// split-K reduce + bias + lrelu + fused BN stats (row length 128 floats)
__global__ void reduce8s(const float* __restrict__ part, const float* __restrict__ bias,
                         float* __restrict__ out, int nf4, int parts, float* __restrict__ slots){
    int tid = threadIdx.x;
    int i = blockIdx.x*256 + tid;
    float4 s = ((const float4*)part)[i];
    for (int z = 1; z < parts; z++){
        float4 p = ((const float4*)part)[(size_t)z*nf4 + i];
        s.x += p.x; s.y += p.y; s.z += p.z; s.w += p.w;
    }
    int c0 = (i & 31) << 2;
    s.x = lrelu(s.x + bias[c0+0]); s.y = lrelu(s.y + bias[c0+1]);
    s.z = lrelu(s.z + bias[c0+2]); s.w = lrelu(s.w + bias[c0+3]);
    ((float4*)out)[i] = s;
    __shared__ float S[128], Q[128];
    if (tid < 128){ S[tid] = 0.f; Q[tid] = 0.f; }
    __syncthreads();
    atomicAdd(&S[c0+0], s.x); atomicAdd(&Q[c0+0], s.x*s.x);
    atomicAdd(&S[c0+1], s.y); atomicAdd(&Q[c0+1], s.y*s.y);
    atomicAdd(&S[c0+2], s.z); atomicAdd(&Q[c0+2], s.z*s.z);
    atomicAdd(&S[c0+3], s.w); atomicAdd(&Q[c0+3], s.w*s.w);
    __syncthreads();
    if (tid < 128){
        int slot = blockIdx.x & 31;
        atomicAdd(&slots[slot*256 + tid], S[tid]);
        atomicAdd(&slots[slot*256 + 128 + tid], Q[tid]);
    }
}

// ---------------------------------------------------------------- BatchNorm
__global__ void bn_stats_v2(const float* __restrict__ x, float* __restrict__ slots, int rows){
    int cg = threadIdx.x & 31, rg = threadIdx.x >> 5;
    float4 s = {0,0,0,0}, q = {0,0,0,0};
    for (int r = blockIdx.x*8 + rg; r < rows; r += gridDim.x*8){
        float4 v = ((const float4*)x)[(size_t)r*32 + cg];
        s.x += v.x; q.x += v.x*v.x;
        s.y += v.y; q.y += v.y*v.y;
        s.z += v.z; q.z += v.z*v.z;
        s.w += v.w; q.w += v.w*v.w;
    }
    __shared__ float S[128], Q[128];
    if (threadIdx.x < 128){ S[threadIdx.x] = 0.f; Q[threadIdx.x] = 0.f; }
    __syncthreads();
    int c0 = cg << 2;
    atomicAdd(&S[c0+0], s.x); atomicAdd(&Q[c0+0], q.x);
    atomicAdd(&S[c0+1], s.y); atomicAdd(&Q[c0+1], q.y);
    atomicAdd(&S[c0+2], s.z); atomicAdd(&Q[c0+2], q.z);
    atomicAdd(&S[c0+3], s.w); atomicAdd(&Q[c0+3], q.w);
    __syncthreads();
    if (threadIdx.x < 128){
        int slot = blockIdx.x & 31;
        atomicAdd(&slots[slot*256 + threadIdx.x], S[threadIdx.x]);
        atomicAdd(&slots[slot*256 + 128 + threadIdx.x], Q[threadIdx.x]);
    }
}

__global__ void bn_finalize2(const float* __restrict__ slots, int nslots,
                             const float* __restrict__ g, const float* __restrict__ b,
                             float invR, float* __restrict__ coef){
    int c = threadIdx.x;
    float s = 0.f, q = 0.f;
    for (int k = 0; k < nslots; k++){ s += slots[k*256 + c]; q += slots[k*256 + 128 + c]; }
    float m = s*invR;
    float v = q*invR - m*m;
    float sc = g[c]*rsqrtf(v + EPSV);
    coef[c] = sc;
    coef[128 + c] = b[c] - m*sc;
}

__global__ void bn_apply4(float4* __restrict__ x, const float* __restrict__ coef, size_t n4){
    size_t i = (size_t)blockIdx.x*blockDim.x + threadIdx.x;
    size_t stride = (size_t)gridDim.x*blockDim.x;
    for (; i < n4; i += stride){
        int c0 = (int)(i & 31) * 4;
        float4 v = x[i];
        v.x = v.x*coef[c0+0] + coef[128+c0+0];
        v.y = v.y*coef[c0+1] + coef[128+c0+1];
        v.z = v.z*coef[c0+2] + coef[128+c0+2];
        v.w = v.w*coef[c0+3] + coef[128+c0+3];
        x[i] = v;
    }
}

// ---------------------------------------------------------------- segment ops
__global__ void seg_sum_edge(const int* __restrict__ eoff, const int* __restrict__ eperm,
                             const int* __restrict__ he_n, const float* __restrict__ h,
                             float* __restrict__ out){
    int m = blockIdx.x, c = threadIdx.x;
    int s0 = eoff[m], cnt = eoff[m+1] - s0;
    __shared__ int sn[128];
    float acc = 0.f;
    for (int base = 0; base < cnt; base += 128){
        int i = base + c;
        if (i < cnt) sn[c] = he_n[eperm[s0+i]];
        __syncthreads();
        int lim = min(128, cnt - base);
        for (int j = 0; j < lim; j++) acc += h[(size_t)sn[j]*128 + c];
        __syncthreads();
    }
    out[(size_t)m*128 + c] = acc;
}

template<int H>
__global__ void row_att(const float* __restrict__ xt, const float* __restrict__ att,
                        int aoff, float* __restrict__ out){
    int n = blockIdx.x, lane = threadIdx.x;
#pragma unroll
    for (int h = 0; h < H; h++){
        const float* xr = xt + (size_t)n*(H*128) + h*128;
        const float* ar = att + h*256 + aoff;
        float s = xr[lane]*ar[lane] + xr[lane+64]*ar[lane+64];
        for (int d = 32; d > 0; d >>= 1) s += __shfl_down(s, d);
        if (lane == 0) out[n*H + h] = s;
    }
}

template<int H>
__global__ void seg_softmax(const int* __restrict__ eoff, const int* __restrict__ eperm,
                            const int* __restrict__ he_n,
                            const float* __restrict__ ax, const float* __restrict__ ae,
                            float* __restrict__ alpha){
    int m = blockIdx.x, t = threadIdx.x;
    int s0 = eoff[m], cnt = eoff[m+1] - s0;
    if (cnt == 0) return;
    __shared__ float red[128];
    float aeh[H];
#pragma unroll
    for (int h = 0; h < H; h++) aeh[h] = ae[m*H + h];
    float lmax[H];
#pragma unroll
    for (int h = 0; h < H; h++) lmax[h] = -1e30f;
    for (int i = t; i < cnt; i += 128){
        int k = eperm[s0+i]; int n = he_n[k];
#pragma unroll
        for (int h = 0; h < H; h++){
            float v = lrelu(ax[n*H + h] + aeh[h]);
            alpha[(size_t)k*H + h] = v;
            lmax[h] = fmaxf(lmax[h], v);
        }
    }
    float gmax[H];
#pragma unroll
    for (int h = 0; h < H; h++){
        red[t] = lmax[h]; __syncthreads();
        for (int s = 64; s > 0; s >>= 1){ if (t < s) red[t] = fmaxf(red[t], red[t+s]); __syncthreads(); }
        gmax[h] = red[0]; __syncthreads();
    }
    float lsum[H];
#pragma unroll
    for (int h = 0; h < H; h++) lsum[h] = 0.f;
    for (int i = t; i < cnt; i += 128){
        int k = eperm[s0+i];
#pragma unroll
        for (int h = 0; h < H; h++){
            float ex = __expf(alpha[(size_t)k*H + h] - gmax[h]);
            alpha[(size_t)k*H + h] = ex;
            lsum[h] += ex;
        }
    }
    float ginv[H];
#pragma unroll
    for (int h = 0; h < H; h++){
        red[t] = lsum[h]; __syncthreads();
        for (int s = 64; s > 0; s >>= 1){ if (t < s) red[t] += red[t+s]; __syncthreads(); }
        ginv[h] = 1.f/red[0]; __syncthreads();
    }
    for (int i = t; i < cnt; i += 128){
        int k = eperm[s0+i];
#pragma unroll
        for (int h = 0; h < H; h++) alpha[(size_t)k*H + h] *= ginv[h];
    }
}

__global__ void seg_eo4(const int* __restrict__ eoff, const int* __restrict__ eperm,
                        const int* __restrict__ he_n,
                        const float* __restrict__ alpha, const float* __restrict__ xt,
                        float* __restrict__ eo){
    int m = blockIdx.x;
    int c = threadIdx.x & 127, hb = threadIdx.x >> 7;   // hb in {0,1}
    int s0 = eoff[m], cnt = eoff[m+1] - s0;
    __shared__ int sn[128];
    __shared__ float sa[128][4];
    float acc0 = 0.f, acc1 = 0.f;
    for (int base = 0; base < cnt; base += 128){
        int i = base + threadIdx.x;
        if (threadIdx.x < 128 && i < cnt){
            int k = eperm[s0+i];
            sn[threadIdx.x] = he_n[k];
#pragma unroll
            for (int h = 0; h < 4; h++) sa[threadIdx.x][h] = alpha[(size_t)k*4 + h];
        }
        __syncthreads();
        int lim = min(128, cnt - base);
        for (int j = 0; j < lim; j++){
            const float* xr = xt + (size_t)sn[j]*512;
            acc0 += sa[j][hb]   * xr[hb*128 + c];
            acc1 += sa[j][hb+2] * xr[(hb+2)*128 + c];
        }
        __syncthreads();
    }
    float binv = cnt > 0 ? 1.f/(float)cnt : 0.f;
    eo[(size_t)m*512 + hb*128 + c]     = acc0*binv;
    eo[(size_t)m*512 + (hb+2)*128 + c] = acc1*binv;
}

__global__ void seg_eo1(const int* __restrict__ eoff, const int* __restrict__ eperm,
                        const int* __restrict__ he_n,
                        const float* __restrict__ alpha, const float* __restrict__ xt,
                        float* __restrict__ eo){
    int m = blockIdx.x, c = threadIdx.x;
    int s0 = eoff[m], cnt = eoff[m+1] - s0;
    __shared__ int sn[128];
    __shared__ float sa[128];
    float acc = 0.f;
    for (int base = 0; base < cnt; base += 128){
        int i = base + c;
        if (i < cnt){
            int k = eperm[s0+i];
            sn[c] = he_n[k];
            sa[c] = alpha[k];
        }
        __syncthreads();
        int lim = min(128, cnt - base);
        for (int j = 0; j < lim; j++) acc += sa[j]*xt[(size_t)sn[j]*128 + c];
        __syncthreads();
    }
    float binv = cnt > 0 ? 1.f/(float)cnt : 0.f;
    eo[(size_t)m*128 + c] = acc*binv;
}

template<int H>
__global__ void seg_node_out(const int* __restrict__ noff, const int* __restrict__ nperm,
                             const int* __restrict__ he_e,
                             const float* __restrict__ alpha, const float* __restrict__ eo,
                             const float* __restrict__ hin, const float* __restrict__ bias,
                             float* __restrict__ hout){
    int n = blockIdx.x, c = threadIdx.x;
    int s0 = noff[n], cnt = noff[n+1] - s0;
    float acc = 0.f;
    for (int i = 0; i < cnt; i++){
        int k = nperm[s0+i]; int e = he_e[k];
        const float* er = eo + (size_t)e*(128*H);
#pragma unroll
        for (int h = 0; h < H; h++) acc += alpha[(size_t)k*H + h]*er[h*128 + c];
    }
    float dinv = cnt > 0 ? 1.f/((float)cnt*(float)H) : 0.f;
    hout[(size_t)n*128 + c] = hin[(size_t)n*128 + c] + bias[c] + acc*dinv;
}

// ---------------------------------------------------------------- launcher
extern "C" void kernel_launch(void* const* d_in, const int* in_sizes, int n_in,
                              void* d_out, int out_size, void* d_ws, size_t ws_size,
                              hipStream_t stream){
    const float* x    = (const float*)d_in[0];
    const int*   he_n = (const int*)  d_in[1];
    const int*   he_e = (const int*)  d_in[2];
    const float* W1   = (const float*)d_in[3];
    const float* b1   = (const float*)d_in[4];
    const float* g1   = (const float*)d_in[5];
    const float* be1  = (const float*)d_in[6];
    const float* Wh1  = (const float*)d_in[7];
    const float* att1 = (const float*)d_in[8];
    const float* bh1  = (const float*)d_in[9];
    const float* g2   = (const float*)d_in[10];
    const float* be2  = (const float*)d_in[11];
    const float* Wh2  = (const float*)d_in[12];
    const float* att2 = (const float*)d_in[13];
    const float* bh2  = (const float*)d_in[14];
    const float* g3   = (const float*)d_in[15];
    const float* be3  = (const float*)d_in[16];
    const float* W3   = (const float*)d_in[17];
    const float* b3   = (const float*)d_in[18];
    const float* g4   = (const float*)d_in[19];
    const float* be4  = (const float*)d_in[20];
    float* out = (float*)d_out;

    char* ws = (char*)d_ws;
    size_t off = 0;
    auto alloc = [&](size_t bytes)->char*{ char* p = ws + off; off += (bytes + 255) & ~(size_t)255; return p; };

    float* hall1  = (float*)alloc((size_t)MALL*128*4);
    float* hall2  = (float*)alloc((size_t)MALL*128*4);
    float* h3     = (float*)alloc((size_t)NN*128*4);
    float* xt1    = (float*)alloc((size_t)MALL*512*4);
    float* xt2    = (float*)alloc((size_t)MALL*128*4);
    float* eo     = (float*)alloc((size_t)MME*512*4);
    float* alpha  = (float*)alloc((size_t)NNZK*4*4);
    float* ax     = (float*)alloc((size_t)NN*4*4);
    float* ae     = (float*)alloc((size_t)MME*4*4);
    float* slots  = (float*)alloc((size_t)32*256*4);
    float* coef   = (float*)alloc(256*4);
    float* part   = (float*)alloc((size_t)8*NN*128*4);
    __hip_bfloat16* W1T  = (__hip_bfloat16*)alloc((size_t)128*DIN*2);
    __hip_bfloat16* Wh1T = (__hip_bfloat16*)alloc((size_t)512*128*2);
    __hip_bfloat16* Wh2T = (__hip_bfloat16*)alloc((size_t)128*128*2);
    __hip_bfloat16* W3T  = (__hip_bfloat16*)alloc((size_t)DIN*128*2);
    int* ecnt  = (int*)alloc(MME*4);      // ncnt allocated immediately after (4096 B, stays adjacent)
    int* ncnt  = (int*)alloc(NN*4);
    int* eoffb = (int*)alloc((MME+1)*4);
    int* ecur  = (int*)alloc(MME*4);
    int* noffb = (int*)alloc((NN+1)*4);
    int* ncur  = (int*)alloc(NN*4);
    int* eperm = (int*)alloc((size_t)NNZK*4);
    int* nperm = (int*)alloc((size_t)NNZK*4);

    // ---- CSR build ----
    zero_i<<<(MME+NN+255)/256, 256, 0, stream>>>(ecnt, MME+NN);   // ecnt+ncnt adjacent
    count_seg<<<NNZK/256, 256, 0, stream>>>(he_n, he_e, ncnt, ecnt);
    scan_excl<<<1, 1024, 0, stream>>>(ecnt, eoffb, MME);
    scan_excl<<<1, 1024, 0, stream>>>(ncnt, noffb, NN);
    copy_i<<<(MME+255)/256, 256, 0, stream>>>(eoffb, ecur, MME);
    copy_i<<<(NN+255)/256, 256, 0, stream>>>(noffb, ncur, NN);
    fill_perm<<<NNZK/256, 256, 0, stream>>>(he_e, ecur, eperm);
    fill_perm<<<NNZK/256, 256, 0, stream>>>(he_n, ncur, nperm);

    // ---- weight transpose+convert ----
    wconv_t<<<dim3(128/32, DIN/32), 256, 0, stream>>>(W1,  W1T,  DIN, 128);
    wconv_t<<<dim3(512/32, 128/32), 256, 0, stream>>>(Wh1, Wh1T, 128, 512);
    wconv_t<<<dim3(128/32, 128/32), 256, 0, stream>>>(Wh2, Wh2T, 128, 128);
    wconv_t<<<dim3(DIN/32, 128/32), 256, 0, stream>>>(W3,  W3T,  128, DIN);

    // ---- layer 0: h1 = lrelu(x @ W1 + b1); BN1 (stats fused in reduce8s) ----
    gemm_nt<0><<<dim3(1, NN/128, 8), 256, 0, stream>>>(x, W1T, part, nullptr, nullptr, nullptr, NN, 128, DIN, DIN/8);
    zero_f<<<32, 256, 0, stream>>>(slots, 32*256);
    reduce8s<<<NN*128/4/256, 256, 0, stream>>>(part, b1, hall1, NN*128/4, 8, slots);
    bn_finalize2<<<1, 128, 0, stream>>>(slots, 32, g1, be1, 1.f/NN, coef);
    bn_apply4<<<1024, 256, 0, stream>>>((float4*)hall1, coef, (size_t)NN*32);

    // ---- hconv1 (heads=4) ----
    seg_sum_edge<<<MME, 128, 0, stream>>>(eoffb, eperm, he_n, hall1, hall1 + (size_t)NN*128);
    gemm_nt<0><<<dim3(512/128, MALL/128, 1), 256, 0, stream>>>(hall1, Wh1T, xt1, nullptr, nullptr, nullptr, MALL, 512, 128, 128);
    row_att<4><<<NN, 64, 0, stream>>>(xt1, att1, 0, ax);
    row_att<4><<<MME, 64, 0, stream>>>(xt1 + (size_t)NN*512, att1, 128, ae);
    seg_softmax<4><<<MME, 128, 0, stream>>>(eoffb, eperm, he_n, ax, ae, alpha);
    seg_eo4<<<MME, 256, 0, stream>>>(eoffb, eperm, he_n, alpha, xt1, eo);
    seg_node_out<4><<<NN, 128, 0, stream>>>(noffb, nperm, he_e, alpha, eo, hall1, bh1, hall2);
    zero_f<<<32, 256, 0, stream>>>(slots, 32*256);
    bn_stats_v2<<<256, 256, 0, stream>>>(hall2, slots, NN);
    bn_finalize2<<<1, 128, 0, stream>>>(slots, 32, g2, be2, 1.f/NN, coef);
    bn_apply4<<<1024, 256, 0, stream>>>((float4*)hall2, coef, (size_t)NN*32);

    // ---- hconv2 (heads=1) ----
    seg_sum_edge<<<MME, 128, 0, stream>>>(eoffb, eperm, he_n, hall2, hall2 + (size_t)NN*128);
    gemm_nt<0><<<dim3(1, MALL/128, 1), 256, 0, stream>>>(hall2, Wh2T, xt2, nullptr, nullptr, nullptr, MALL, 128, 128, 128);
    row_att<1><<<NN, 64, 0, stream>>>(xt2, att2, 0, ax);
    row_att<1><<<MME, 64, 0, stream>>>(xt2 + (size_t)NN*128, att2, 128, ae);
    seg_softmax<1><<<MME, 128, 0, stream>>>(eoffb, eperm, he_n, ax, ae, alpha);
    seg_eo1<<<MME, 128, 0, stream>>>(eoffb, eperm, he_n, alpha, xt2, eo);
    seg_node_out<1><<<NN, 128, 0, stream>>>(noffb, nperm, he_e, alpha, eo, hall2, bh2, h3);
    zero_f<<<32, 256, 0, stream>>>(slots, 32*256);
    bn_stats_v2<<<256, 256, 0, stream>>>(h3, slots, NN);
    bn_finalize2<<<1, 128, 0, stream>>>(slots, 32, g3, be3, 1.f/NN, coef);
    bn_apply4<<<1024, 256, 0, stream>>>((float4*)h3, coef, (size_t)NN*32);

    // ---- final: out = BN4(x + lrelu(h3 @ W3 + b3)) — two-pass, no 256MB apply ----
    zero_f<<<32, 256, 0, stream>>>(slots, 32*256);
    gemm_stats<<<dim3(DIN/128, NN/128), 256, 0, stream>>>(h3, W3T, b3, x, slots, NN, DIN, 128, 128);
    bn_finalize2<<<1, 128, 0, stream>>>(slots, 32, g4, be4, 1.f/((float)NN*TT), coef);
    gemm_nt<1><<<dim3(DIN/128, NN/128, 1), 256, 0, stream>>>(h3, W3T, out, b3, x, coef, NN, DIN, 128, 128);
}